// Round 5
// baseline (12418.589 us; speedup 1.0000x reference)
//
#include <hip/hip_runtime.h>
#include <cstdint>
#include <cstddef>

// ---------------------------------------------------------------------------
// SNN "CatNet" forward.
// Spiking tensors: uint8 [(n*64+t), C, H, W]. Conv outputs staged f32,
// chunked over n (64 t-slices at a time) to bound workspace ~110 MB.
// Outputs written as f32 (reference output dtype). Inputs in dict order.
// ---------------------------------------------------------------------------

__global__ __launch_bounds__(256) void k_transpose_x(const float* __restrict__ x,
                                                     float* __restrict__ XT) {
  int idx = blockIdx.x * 256 + threadIdx.x;           // over 256*3*1024
  int b = idx / 3072;                                  // (n*64+t)
  int rem = idx - b * 3072;                            // c*1024+hw
  int t = b & 63, n = b >> 6;
  XT[idx] = x[((size_t)(n * 3072 + rem)) * 64 + t];
}

__global__ __launch_bounds__(256) void k_xbar(const float* __restrict__ x,
                                              float* __restrict__ xbar) {
  int idx = blockIdx.x * 256 + threadIdx.x;           // over 4*3*1024
  if (idx >= 12288) return;
  const float* p = x + (size_t)idx * 64;
  float s = 0.f;
  #pragma unroll
  for (int t = 0; t < 64; ++t) s += p[t];
  xbar[idx] = s * 0.015625f;
}

template <typename T>
__device__ __forceinline__ float ldval(const T* p, size_t i);
template <> __device__ __forceinline__ float ldval<float>(const float* p, size_t i) { return p[i]; }
template <> __device__ __forceinline__ float ldval<uint8_t>(const uint8_t* p, size_t i) { return (float)p[i]; }

// Generic pad=1 3x3 conv, square H=W (8-divisible). Tile: 64 co x 8x8 px.
template <typename T>
__global__ __launch_bounds__(256) void k_conv(const T* __restrict__ in,
                                              const float* __restrict__ wt,
                                              const float* __restrict__ bs,
                                              float* __restrict__ out,
                                              int Ci, int Co, int H) {
  const int W = H;
  __shared__ float sW[4608];   // [ci*9+k][64 co]
  __shared__ float sI[960];    // [ci][10 rows][stride 12]
  const int tid = threadIdx.x;
  const int tilesW = W >> 3;
  const int h0 = (blockIdx.x / tilesW) * 8;
  const int w0 = (blockIdx.x % tilesW) * 8;
  const int co0 = blockIdx.y * 64;
  const int b = blockIdx.z;
  const int px = tid & 15;
  const int cog = tid >> 4;
  const int prow = px >> 1;
  const int pcol = (px & 1) * 4;
  float acc[4][4] = {};
  const size_t inB = (size_t)b * Ci * H * W;
  for (int ci0 = 0; ci0 < Ci; ci0 += 8) {
    const int cnt = (Ci - ci0 < 8) ? (Ci - ci0) : 8;
    const int c9 = cnt * 9;
    const int totW = 64 * c9;
    for (int e = tid; e < totW; e += 256) {
      int co = e / c9, r = e - co * c9;
      int ci = r / 9, k = r - ci * 9;
      sW[(ci * 9 + k) * 64 + co] = wt[((size_t)(co0 + co) * Ci + (ci0 + ci)) * 9 + k];
    }
    const int totI = cnt * 100;
    for (int e = tid; e < totI; e += 256) {
      int ci = e / 100, r = e - ci * 100;
      int rr = r / 10, rc = r - rr * 10;
      int ih = h0 - 1 + rr, iw = w0 - 1 + rc;
      float v = 0.f;
      if (ih >= 0 && ih < H && iw >= 0 && iw < W)
        v = ldval(in, inB + (size_t)(ci0 + ci) * H * W + ih * W + iw);
      sI[ci * 120 + rr * 12 + rc] = v;
    }
    __syncthreads();
    for (int ci = 0; ci < cnt; ++ci) {
      const float* sWc = &sW[ci * 576 + cog * 4];
      const float* sIc = &sI[ci * 120 + prow * 12 + pcol];
      #pragma unroll
      for (int kh = 0; kh < 3; ++kh) {
        #pragma unroll
        for (int kw = 0; kw < 3; ++kw) {
          const float* wp = sWc + (kh * 3 + kw) * 64;
          const float w0v = wp[0], w1v = wp[1], w2v = wp[2], w3v = wp[3];
          const float* ip = sIc + kh * 12 + kw;
          const float i0 = ip[0], i1 = ip[1], i2 = ip[2], i3 = ip[3];
          acc[0][0] += w0v * i0; acc[0][1] += w0v * i1; acc[0][2] += w0v * i2; acc[0][3] += w0v * i3;
          acc[1][0] += w1v * i0; acc[1][1] += w1v * i1; acc[1][2] += w1v * i2; acc[1][3] += w1v * i3;
          acc[2][0] += w2v * i0; acc[2][1] += w2v * i1; acc[2][2] += w2v * i2; acc[2][3] += w2v * i3;
          acc[3][0] += w3v * i0; acc[3][1] += w3v * i1; acc[3][2] += w3v * i2; acc[3][3] += w3v * i3;
        }
      }
    }
    __syncthreads();
  }
  const size_t outB = (size_t)b * Co * H * W;
  #pragma unroll
  for (int i = 0; i < 4; ++i) {
    const int co = co0 + cog * 4 + i;
    const float bv = bs[co];
    float4 r;
    r.x = acc[i][0] + bv; r.y = acc[i][1] + bv; r.z = acc[i][2] + bv; r.w = acc[i][3] + bv;
    *(float4*)&out[outB + (size_t)co * H * W + (h0 + prow) * W + (w0 + pcol)] = r;
  }
}

// Layer-7 conv: input (B, Ci, 4,4), pad 0 -> output (B, Co, 2,2). Ci % 8 == 0.
template <typename T>
__global__ __launch_bounds__(256) void k_convS(const T* __restrict__ in,
                                               const float* __restrict__ wt,
                                               const float* __restrict__ bs,
                                               float* __restrict__ out,
                                               int Ci, int Co, int B) {
  __shared__ float sW[4608];
  __shared__ float sIn[2112];   // [16 b][stride 132]: 8 ci * 16 px + pad
  const int tid = threadIdx.x;
  const int bg = tid & 15;
  const int cog = tid >> 4;
  const int b = blockIdx.x * 16 + bg;
  const int co0 = blockIdx.y * 64;
  float acc[4][4] = {};
  for (int ci0 = 0; ci0 < Ci; ci0 += 8) {
    for (int e = tid; e < 4608; e += 256) {
      int co = e / 72, r = e - co * 72;
      int ci = r / 9, k = r - ci * 9;
      sW[(ci * 9 + k) * 64 + co] = wt[((size_t)(co0 + co) * Ci + (ci0 + ci)) * 9 + k];
    }
    for (int e = tid; e < 2048; e += 256) {
      int bb = e >> 7, r = e & 127;
      int ci = r >> 4, p = r & 15;
      int gb = blockIdx.x * 16 + bb;
      sIn[bb * 132 + ci * 16 + p] = (gb < B) ? ldval(in, ((size_t)gb * Ci + ci0 + ci) * 16 + p) : 0.f;
    }
    __syncthreads();
    for (int ci = 0; ci < 8; ++ci) {
      const float* ib = &sIn[bg * 132 + ci * 16];
      const float* sWc = &sW[ci * 576 + cog * 4];
      #pragma unroll
      for (int kh = 0; kh < 3; ++kh) {
        #pragma unroll
        for (int kw = 0; kw < 3; ++kw) {
          const float* wp = sWc + (kh * 3 + kw) * 64;
          const float w0v = wp[0], w1v = wp[1], w2v = wp[2], w3v = wp[3];
          const float i00 = ib[kh * 4 + kw];
          const float i01 = ib[kh * 4 + kw + 1];
          const float i10 = ib[(kh + 1) * 4 + kw];
          const float i11 = ib[(kh + 1) * 4 + kw + 1];
          acc[0][0] += w0v * i00; acc[0][1] += w0v * i01; acc[0][2] += w0v * i10; acc[0][3] += w0v * i11;
          acc[1][0] += w1v * i00; acc[1][1] += w1v * i01; acc[1][2] += w1v * i10; acc[1][3] += w1v * i11;
          acc[2][0] += w2v * i00; acc[2][1] += w2v * i01; acc[2][2] += w2v * i10; acc[2][3] += w2v * i11;
          acc[3][0] += w3v * i00; acc[3][1] += w3v * i01; acc[3][2] += w3v * i10; acc[3][3] += w3v * i11;
        }
      }
    }
    __syncthreads();
  }
  if (b < B) {
    const size_t outB = (size_t)b * Co * 4;
    #pragma unroll
    for (int i = 0; i < 4; ++i) {
      int co = co0 + cog * 4 + i;
      float bv = bs[co];
      float4 r;
      r.x = acc[i][0] + bv; r.y = acc[i][1] + bv; r.z = acc[i][2] + bv; r.w = acc[i][3] + bv;
      *(float4*)&out[outB + (size_t)co * 4] = r;
    }
  }
}

// 2x2 average pool over uint8 spikes -> f32; in (B,C,H,H), out (B,C,H/2,H/2).
__global__ __launch_bounds__(256) void k_pool_u8(const uint8_t* __restrict__ in,
                                                 float* __restrict__ out,
                                                 int H, int total) {
  int idx = blockIdx.x * 256 + threadIdx.x;
  if (idx >= total) return;
  int Wo = H >> 1;
  int wo = idx % Wo;
  int t1 = idx / Wo;
  int ho = t1 % Wo;
  int bc = t1 / Wo;
  size_t base = ((size_t)bc * H + 2 * ho) * H + 2 * wo;
  out[idx] = 0.25f * ((float)in[base] + (float)in[base + 1] +
                      (float)in[base + H] + (float)in[base + H + 1]);
}

// f32 avgpool (analog path)
__global__ __launch_bounds__(256) void k_pool_f32(const float* __restrict__ in,
                                                  float* __restrict__ out,
                                                  int H, int total) {
  int idx = blockIdx.x * 256 + threadIdx.x;
  if (idx >= total) return;
  int Wo = H >> 1;
  int wo = idx % Wo;
  int t1 = idx / Wo;
  int ho = t1 % Wo;
  int bc = t1 / Wo;
  size_t base = ((size_t)bc * H + 2 * ho) * H + 2 * wo;
  out[idx] = 0.25f * (in[base] + in[base + 1] + in[base + H] + in[base + H + 1]);
}

// Integrate-and-fire over one n-chunk (64 t-slices): X [(t),C,HW] f32 ->
// Sp [(t),C,HW] u8 spikes; accumulates per-channel spike count into ssum.
__global__ __launch_bounds__(256) void k_if(const float* __restrict__ X,
                                            uint8_t* __restrict__ Sp,
                                            const float* __restrict__ th,
                                            float* __restrict__ ssum,
                                            int C, int HW) {
  int idx = blockIdx.x * 256 + threadIdx.x;   // over C*HW
  const int CHW = C * HW;
  if (idx >= CHW) return;
  int c = idx / HW;
  const float thv = th[c];
  const float* p = X + idx;
  uint8_t* q = Sp + idx;
  float v = 0.f, ss = 0.f;
  #pragma unroll
  for (int t = 0; t < 64; ++t) {
    v += p[(size_t)t * CHW];
    float s = (v >= thv) ? 1.f : 0.f;
    v -= s * thv;
    q[(size_t)t * CHW] = (uint8_t)s;
    ss += s;
  }
  if ((HW & 63) == 0) {   // wave-uniform channel -> shuffle reduce
    for (int off = 32; off >= 1; off >>= 1) ss += __shfl_down(ss, off);
    if ((threadIdx.x & 63) == 0) atomicAdd(&ssum[c], ss);
  } else {
    atomicAdd(&ssum[c], ss);
  }
}

// Analog quantize: y = clip(floor(y4*64)/64, 0, 1); accumulates y sum/ch.
__global__ __launch_bounds__(256) void k_tty(const float* __restrict__ y4,
                                             float* __restrict__ yout,
                                             float* __restrict__ ysum,
                                             int C, int HW) {
  int idx = blockIdx.x * 256 + threadIdx.x;   // over 4*C*HW
  int rem = idx % (C * HW);
  int c = rem / HW;
  float v = floorf(y4[idx] * 64.f) * 0.015625f;
  v = fminf(fmaxf(v, 0.f), 1.f);
  yout[idx] = v;
  if ((HW & 63) == 0) {
    for (int off = 32; off >= 1; off >>= 1) v += __shfl_down(v, off);
    if ((threadIdx.x & 63) == 0) atomicAdd(&ysum[c], v);
  } else {
    atomicAdd(&ysum[c], v);
  }
}

__global__ void k_thr(const float* __restrict__ thin,
                      const float* __restrict__ ssum,
                      const float* __restrict__ ysum,
                      float* __restrict__ dst, int C, float invmul) {
  int c = blockIdx.x * 256 + threadIdx.x;
  if (c >= C) return;
  float diff = (ysum[c] * 64.f - ssum[c]) * invmul;
  dst[c] = thin[c] - 0.1f * diff;
}

// Sum final spikes over t: A[(n*64+t), 1024] u8 -> S[n, 1024] f32
__global__ void k_sumspk(const uint8_t* __restrict__ A, float* __restrict__ S) {
  int idx = blockIdx.x * 256 + threadIdx.x;   // over 4096
  if (idx >= 4096) return;
  int n = idx >> 10, c = idx & 1023;
  const uint8_t* p = A + (size_t)n * 64 * 1024 + c;
  float s = 0.f;
  #pragma unroll
  for (int t = 0; t < 64; ++t) s += (float)p[t * 1024];
  S[idx] = s;
}

__global__ void k_cls(const float* __restrict__ S, const float* __restrict__ wc,
                      const float* __restrict__ bcp, float* __restrict__ out) {
  int idx = blockIdx.x * 256 + threadIdx.x;
  if (idx >= 400) return;
  int n = idx / 100, o = idx - (idx / 100) * 100;
  const float* sp = S + n * 1024;
  const float* wp = wc + o * 1024;
  float acc = 0.f;
  for (int c = 0; c < 1024; ++c) acc += wp[c] * sp[c];
  out[idx] = acc * 0.015625f + bcp[o];
}

extern "C" void kernel_launch(void* const* d_in, const int* in_sizes, int n_in,
                              void* d_out_v, int out_size, void* d_ws, size_t ws_size,
                              hipStream_t stream) {
  // Inputs in setup_inputs() dict order:
  //  [w1s,b1s,w1a,b1a, ..., w7s,b7s,w7a,b7a] (0..27), wc(28), bc(29), x(30),
  //  threshold_pre_1..7 (31..37), p1..p4 (38..41)
  const float *Ws[7], *Bs[7], *Wa[7], *Ba[7];
  for (int i = 0; i < 7; ++i) {
    Ws[i] = (const float*)d_in[i * 4 + 0];
    Bs[i] = (const float*)d_in[i * 4 + 1];
    Wa[i] = (const float*)d_in[i * 4 + 2];
    Ba[i] = (const float*)d_in[i * 4 + 3];
  }
  const float* wc = (const float*)d_in[28];
  const float* bc = (const float*)d_in[29];
  const float* x  = (const float*)d_in[30];
  const float* TH[7];
  for (int i = 0; i < 7; ++i) TH[i] = (const float*)d_in[31 + i];
  const float* P[4];
  for (int i = 0; i < 4; ++i) P[i] = (const float*)d_in[38 + i];
  float* out = (float*)d_out_v;

  // ---- workspace layout (f32 buffers first, then u8) ----
  float* w = (float*)d_ws;
  size_t off = 0;
  float* XT   = w + off; off += 786432;     // (256,3,32,32) f32
  float* CF   = w + off; off += 8388608;    // conv/pool f32 staging (33.5 MB)
  float* xbar = w + off; off += 12288;      // (4,3,32,32)
  float* yA   = w + off; off += 524288;
  float* yB   = w + off; off += 524288;
  float* y4   = w + off; off += 524288;
  float* S    = w + off; off += 4096;
  float* sums = w + off; off += 11 * 2048;  // per-stage [ssum(1024)|ysum(1024)]
  uint8_t* ub = (uint8_t*)(w + off);
  size_t uoff = 0;
  uint8_t* SA = ub + uoff; uoff += 33554432;  // spikes ping (max 256*128*1024)
  uint8_t* SB = ub + uoff; uoff += 33554432;  // spikes pong
  size_t total_bytes = off * sizeof(float) + uoff;
  if (ws_size < total_bytes) return;   // ~110.3 MB required

  hipMemsetAsync(sums, 0, 11 * 2048 * sizeof(float), stream);
  k_transpose_x<<<3072, 256, 0, stream>>>(x, XT);
  k_xbar<<<48, 256, 0, stream>>>(x, xbar);

  int stage = 0;

  // Spiking conv layer (pad=1), chunked over n: inS/outS u8 unless L1 (f32 XT).
  auto conv_stage = [&](const void* inS, bool inF32, uint8_t* outS,
                        const float* inY, float* outY,
                        int li, int Ci, int Co, int H, const float* thin, int outoff) {
    const int HW = H * H;
    float* ss = sums + stage * 2048;
    float* ys = ss + 1024;
    dim3 g((H / 8) * (H / 8), Co / 64, 64);
    for (int n = 0; n < 4; ++n) {
      if (inF32)
        k_conv<float><<<g, 256, 0, stream>>>((const float*)inS + (size_t)n * 64 * Ci * HW,
                                             Ws[li], Bs[li], CF, Ci, Co, H);
      else
        k_conv<uint8_t><<<g, 256, 0, stream>>>((const uint8_t*)inS + (size_t)n * 64 * Ci * HW,
                                               Ws[li], Bs[li], CF, Ci, Co, H);
      k_if<<<(Co * HW + 255) / 256, 256, 0, stream>>>(CF, outS + (size_t)n * 64 * Co * HW,
                                                      thin, ss, Co, HW);
    }
    dim3 ga((H / 8) * (H / 8), Co / 64, 4);
    k_conv<float><<<ga, 256, 0, stream>>>(inY, Wa[li], Ba[li], y4, Ci, Co, H);
    k_tty<<<(4 * Co * HW + 255) / 256, 256, 0, stream>>>(y4, outY, ys, Co, HW);
    int mul = 4 * HW * 64;
    k_thr<<<(Co + 255) / 256, 256, 0, stream>>>(thin, ss, ys, out + outoff, Co, 1.0f / (float)mul);
    ++stage;
  };

  auto pool_stage = [&](const uint8_t* inS, uint8_t* outS, const float* inY, float* outY,
                        int C, int H, const float* pthr, int outoff) {
    const int Ho = H / 2, HWo = Ho * Ho;
    float* ss = sums + stage * 2048;
    float* ys = ss + 1024;
    int tot5 = 256 * C * HWo;
    k_pool_u8<<<(tot5 + 255) / 256, 256, 0, stream>>>(inS, CF, H, tot5);
    for (int n = 0; n < 4; ++n)
      k_if<<<(C * HWo + 255) / 256, 256, 0, stream>>>(CF + (size_t)n * 64 * C * HWo,
                                                      outS + (size_t)n * 64 * C * HWo,
                                                      pthr, ss, C, HWo);
    int tot4 = 4 * C * HWo;
    k_pool_f32<<<(tot4 + 255) / 256, 256, 0, stream>>>(inY, y4, H, tot4);
    k_tty<<<(tot4 + 255) / 256, 256, 0, stream>>>(y4, outY, ys, C, HWo);
    int mul = 4 * HWo * 64;
    k_thr<<<(C + 255) / 256, 256, 0, stream>>>(pthr, ss, ys, out + outoff, C, 1.0f / (float)mul);
    ++stage;
  };

  // L1: XT f32 -> SA                                out offsets (elements)
  conv_stage(XT, true,  SA, xbar, yA, 0, 3,   128, 32, TH[0], 400);
  // L2: SA -> SB
  conv_stage(SA, false, SB, yA,   yB, 1, 128, 128, 32, TH[1], 528);
  // P1: SB -> SA (32 -> 16)
  pool_stage(SB, SA, yB, yA, 128, 32, P[0], 3216);
  // L3
  conv_stage(SA, false, SB, yA, yB, 2, 128, 256, 16, TH[2], 656);
  // L4
  conv_stage(SB, false, SA, yB, yA, 3, 256, 256, 16, TH[3], 912);
  // P2: 16 -> 8
  pool_stage(SA, SB, yA, yB, 256, 16, P[1], 3344);
  // L5
  conv_stage(SB, false, SA, yB, yA, 4, 256, 512, 8, TH[4], 1168);
  // L6
  conv_stage(SA, false, SB, yA, yB, 5, 512, 512, 8, TH[5], 1680);
  // P3: 8 -> 4
  pool_stage(SB, SA, yB, yA, 512, 8, P[2], 3600);
  // L7: SA (256,512,4,4) -> CF (256,1024,2,2) f32 -> SB u8; pad 0
  {
    float* ss = sums + stage * 2048;
    float* ys = ss + 1024;
    k_convS<uint8_t><<<dim3(16, 16), 256, 0, stream>>>(SA, Ws[6], Bs[6], CF, 512, 1024, 256);
    for (int n = 0; n < 4; ++n)
      k_if<<<(1024 * 4 + 255) / 256, 256, 0, stream>>>(CF + (size_t)n * 64 * 4096,
                                                       SB + (size_t)n * 64 * 4096,
                                                       TH[6], ss, 1024, 4);
    k_convS<float><<<dim3(1, 16), 256, 0, stream>>>(yA, Wa[6], Ba[6], y4, 512, 1024, 4);
    k_tty<<<(4 * 1024 * 4 + 255) / 256, 256, 0, stream>>>(y4, yB, ys, 1024, 4);
    k_thr<<<4, 256, 0, stream>>>(TH[6], ss, ys, out + 2192, 1024, 1.0f / 1024.f);
    ++stage;
  }
  // P4: SB (2x2) -> SA (1x1)
  pool_stage(SB, SA, yB, yA, 1024, 2, P[3], 4112);
  // classifier
  k_sumspk<<<16, 256, 0, stream>>>(SA, S);
  k_cls<<<2, 256, 0, stream>>>(S, wc, bc, out);
}

// Round 6
// 3762.928 us; speedup vs baseline: 3.3002x; 3.3002x over previous
//
#include <hip/hip_runtime.h>
#include <cstdint>
#include <cstddef>

// ---------------------------------------------------------------------------
// SNN "CatNet" forward, MFMA edition.
// Spiking tensors: uint8 [(n*64+t), C, H, W] (values exactly 0/1).
// Analog tensors: f32, values are multiples of 1/64 in [0,1] -> exact bf16.
// Convs 2..7 run as bf16 MFMA implicit-GEMM with hi/lo split weights
// (w = bf16(w) + bf16(w - bf16(w))) for ~fp32 accuracy.
// Weight fragments are pre-transformed per layer into per-lane MFMA layout.
// L1 (K=27, non-exact f32 input) stays on the VALU conv.
// ---------------------------------------------------------------------------

typedef short short8 __attribute__((ext_vector_type(8)));   // 8 bf16
typedef float floatx4 __attribute__((ext_vector_type(4)));

__device__ __forceinline__ unsigned short f2bf_rne(float f) {
  unsigned u = __float_as_uint(f);
  return (unsigned short)((u + 0x7FFFu + ((u >> 16) & 1u)) >> 16);
}

template <typename T>
__device__ __forceinline__ float ldval(const T* p, size_t i);
template <> __device__ __forceinline__ float ldval<float>(const float* p, size_t i) { return p[i]; }
template <> __device__ __forceinline__ float ldval<uint8_t>(const uint8_t* p, size_t i) { return (float)p[i]; }

// ---------------------------------------------------------------------------
// Weight pre-transform: W f32 [Co][Ci][3][3] -> bf16 hi/lo MFMA A-fragments.
// Layout: wt[cotile][chunk][tap][cog][hilo][lane][8]
//   value = W_half[co = cotile*64+cog*16+(lane&15)][ci = chunk*32+(lane>>4)*8+j][tap]
// ---------------------------------------------------------------------------
__global__ __launch_bounds__(256) void k_wxform(const float* __restrict__ Wsrc,
                                                unsigned short* __restrict__ wt,
                                                int Ci, int Co) {
  const int nch = Ci >> 5;
  const int total = (Co >> 6) * nch * 9 * 4 * 64;
  int idx = blockIdx.x * 256 + threadIdx.x;
  if (idx >= total) return;
  int lane = idx & 63;
  int t2 = idx >> 6;
  int cg = t2 & 3;
  int t3 = t2 >> 2;
  int tap = t3 % 9;
  int t4 = t3 / 9;
  int ch = t4 % nch;
  int cot = t4 / nch;
  int co = cot * 64 + cg * 16 + (lane & 15);
  int cib = ch * 32 + (lane >> 4) * 8;
  short8 vh, vl;
  #pragma unroll
  for (int j = 0; j < 8; ++j) {
    float wv = Wsrc[((size_t)co * Ci + cib + j) * 9 + tap];
    unsigned short h = f2bf_rne(wv);
    float hf = __uint_as_float((unsigned)h << 16);
    vh[j] = (short)h;
    vl[j] = (short)f2bf_rne(wv - hf);
  }
  size_t base = ((((size_t)cot * nch + ch) * 9 + tap) * 4 + cg) * 1024 + (size_t)lane * 8;
  *(short8*)&wt[base] = vh;
  *(short8*)&wt[base + 512] = vl;
}

// ---------------------------------------------------------------------------
// MFMA conv. PAD0=false: 3x3 pad=1, square H=W; block tile = 64co x 256px,
//   pixels = NIMG images x TRI rows x W cols (tpi row-tiles per image).
// PAD0=true: L7 geometry, in (img,Ci,4,4) -> out (img,Co,2,2), NIMG=64.
// wt in fragment layout (see k_wxform). 512 threads = 8 waves.
// ---------------------------------------------------------------------------
template <typename T, bool PAD0>
__global__ __launch_bounds__(512) void k_cmfma(
    const T* __restrict__ in, const unsigned short* __restrict__ wt,
    const float* __restrict__ bs, float* __restrict__ out,
    int Ci, int Co, int W, int TRI, int tpi, int NIMG, int nImgValid) {
  constexpr int PPXMAX = PAD0 ? 1024 : 400;
  __shared__ unsigned short sW[36864];          // 9 taps x 4 cog x 2 hilo x 512
  __shared__ unsigned short sIn[PPXMAX * 40];   // [patch px][ci], stride 40
  const int tid = threadIdx.x;
  const int lane = tid & 63;
  const int wv = tid >> 6;
  const int cotile = blockIdx.x;
  const int mtile = blockIdx.y;

  int img_first, r0, TRW, PPR, PPX;
  if constexpr (PAD0) {
    img_first = mtile * 64; r0 = 0; TRW = 4; PPR = 16; PPX = 1024;
  } else {
    img_first = (mtile / tpi) * NIMG;
    r0 = (mtile % tpi) * TRI;
    TRW = TRI * W;
    PPR = (TRI + 2) * (W + 2);
    PPX = NIMG * PPR;
  }
  // per-lane pixel rows for the two 16-px fragments
  int p0[2], mimg[2], mopx[2];
  #pragma unroll
  for (int g = 0; g < 2; ++g) {
    int m = wv * 32 + g * 16 + (lane & 15);
    int limg;
    if constexpr (PAD0) {
      limg = m >> 2;
      int o = m & 3;
      p0[g] = limg * 16 + (o >> 1) * 4 + (o & 1);
      mopx[g] = (o >> 1) * 2 + (o & 1);
    } else {
      limg = m / TRW;
      int rm = m - limg * TRW;
      int r = rm / W, c = rm - r * W;
      p0[g] = limg * PPR + r * (W + 2) + c;
      mopx[g] = (r0 + r) * W + c;
    }
    mimg[g] = img_first + limg;
  }
  int psh[9];
  #pragma unroll
  for (int tap = 0; tap < 9; ++tap) {
    int dh = tap / 3, dw = tap - dh * 3;
    psh[tap] = PAD0 ? (dh * 4 + dw) : (dh * (W + 2) + dw);
  }
  const int kb = (lane >> 4) * 8;
  floatx4 acc[2][4];
  floatx4 zero = {0.f, 0.f, 0.f, 0.f};
  #pragma unroll
  for (int g = 0; g < 2; ++g)
    #pragma unroll
    for (int cg = 0; cg < 4; ++cg) acc[g][cg] = zero;

  const int nch = Ci >> 5;
  const size_t HWin = PAD0 ? 16 : (size_t)W * W;
  for (int ch = 0; ch < nch; ++ch) {
    // ---- stage weight fragments (linear 73728 B copy) ----
    {
      const unsigned short* wsrc = wt + ((size_t)cotile * nch + ch) * 36864;
      #pragma unroll
      for (int it = 0; it < 9; ++it) {
        int o = it * 4096 + tid * 8;
        *(short8*)&sW[o] = *(const short8*)&wsrc[o];
      }
    }
    // ---- stage input patch [px][ci] as bf16 (exact values) ----
    const int ci0 = ch * 32;
    for (int e = tid; e < PPX * 32; e += 512) {
      int ci = e / PPX, p = e - ci * PPX;
      unsigned short v = 0;
      int limg, gpx;
      if constexpr (PAD0) {
        limg = p >> 4;
        gpx = p & 15;
      } else {
        limg = p / PPR;
        int rem = p - limg * PPR;
        int pr = rem / (W + 2), pc = rem - pr * (W + 2);
        int gr = r0 + pr - 1, gc = pc - 1;
        gpx = (gr >= 0 && gr < W && gc >= 0 && gc < W) ? gr * W + gc : -1;
      }
      int img = img_first + limg;
      if (gpx >= 0 && img < nImgValid) {
        float f = ldval(in, ((size_t)img * Ci + ci0 + ci) * HWin + gpx);
        v = f2bf_rne(f);
      }
      sIn[p * 40 + ci] = v;
    }
    __syncthreads();
    // ---- MFMA: D[co][px] += Whi*X + Wlo*X, 9 taps ----
    #pragma unroll
    for (int tap = 0; tap < 9; ++tap) {
      short8 bfr[2];
      #pragma unroll
      for (int g = 0; g < 2; ++g)
        bfr[g] = *(const short8*)&sIn[(p0[g] + psh[tap]) * 40 + kb];
      #pragma unroll
      for (int cg = 0; cg < 4; ++cg) {
        const unsigned short* wb = &sW[((tap * 4 + cg) * 2) * 512 + lane * 8];
        short8 ahi = *(const short8*)wb;
        short8 alo = *(const short8*)(wb + 512);
        #pragma unroll
        for (int g = 0; g < 2; ++g) {
          acc[g][cg] = __builtin_amdgcn_mfma_f32_16x16x32_bf16(ahi, bfr[g], acc[g][cg], 0, 0, 0);
          acc[g][cg] = __builtin_amdgcn_mfma_f32_16x16x32_bf16(alo, bfr[g], acc[g][cg], 0, 0, 0);
        }
      }
    }
    __syncthreads();
  }
  // ---- epilogue: D row=(lane>>4)*4+i -> co, col=lane&15 -> px ----
  const int HWout = PAD0 ? 4 : W * W;
  #pragma unroll
  for (int g = 0; g < 2; ++g) {
    if (mimg[g] >= nImgValid) continue;
    #pragma unroll
    for (int cg = 0; cg < 4; ++cg) {
      #pragma unroll
      for (int i = 0; i < 4; ++i) {
        int co = cotile * 64 + cg * 16 + (lane >> 4) * 4 + i;
        out[((size_t)mimg[g] * Co + co) * HWout + mopx[g]] = acc[g][cg][i] + bs[co];
      }
    }
  }
}

// ---------------------------------------------------------------------------
// L1 VALU conv (pad=1, Ci=3). xlay=1: read x (4,3,32,32,64) directly.
// ---------------------------------------------------------------------------
template <typename T>
__global__ __launch_bounds__(256) void k_conv(const T* __restrict__ in,
                                              const float* __restrict__ wt,
                                              const float* __restrict__ bs,
                                              float* __restrict__ out,
                                              int Ci, int Co, int H,
                                              int xlay, int b0) {
  const int W = H;
  __shared__ float sW[4608];
  __shared__ float sI[960];
  const int tid = threadIdx.x;
  const int tilesW = W >> 3;
  const int h0 = (blockIdx.x / tilesW) * 8;
  const int w0 = (blockIdx.x % tilesW) * 8;
  const int co0 = blockIdx.y * 64;
  const int b = blockIdx.z;
  const int px = tid & 15;
  const int cog = tid >> 4;
  const int prow = px >> 1;
  const int pcol = (px & 1) * 4;
  float acc[4][4] = {};
  const size_t inB = (size_t)b * Ci * H * W;
  for (int ci0 = 0; ci0 < Ci; ci0 += 8) {
    const int cnt = (Ci - ci0 < 8) ? (Ci - ci0) : 8;
    const int c9 = cnt * 9;
    const int totW = 64 * c9;
    for (int e = tid; e < totW; e += 256) {
      int co = e / c9, r = e - co * c9;
      int ci = r / 9, k = r - ci * 9;
      sW[(ci * 9 + k) * 64 + co] = wt[((size_t)(co0 + co) * Ci + (ci0 + ci)) * 9 + k];
    }
    const int totI = cnt * 100;
    for (int e = tid; e < totI; e += 256) {
      int ci = e / 100, r = e - ci * 100;
      int rr = r / 10, rc = r - rr * 10;
      int ih = h0 - 1 + rr, iw = w0 - 1 + rc;
      float v = 0.f;
      if (ih >= 0 && ih < H && iw >= 0 && iw < W) {
        if (xlay) {
          int bg = b0 + b;
          v = ((const float*)in)[(((size_t)(bg >> 6) * Ci + (ci0 + ci)) * (H * W) + ih * W + iw) * 64 + (bg & 63)];
        } else {
          v = ldval(in, inB + (size_t)(ci0 + ci) * H * W + ih * W + iw);
        }
      }
      sI[ci * 120 + rr * 12 + rc] = v;
    }
    __syncthreads();
    for (int ci = 0; ci < cnt; ++ci) {
      const float* sWc = &sW[ci * 576 + cog * 4];
      const float* sIc = &sI[ci * 120 + prow * 12 + pcol];
      #pragma unroll
      for (int kh = 0; kh < 3; ++kh) {
        #pragma unroll
        for (int kw = 0; kw < 3; ++kw) {
          const float* wp = sWc + (kh * 3 + kw) * 64;
          const float w0v = wp[0], w1v = wp[1], w2v = wp[2], w3v = wp[3];
          const float* ip = sIc + kh * 12 + kw;
          const float i0 = ip[0], i1 = ip[1], i2 = ip[2], i3 = ip[3];
          acc[0][0] += w0v * i0; acc[0][1] += w0v * i1; acc[0][2] += w0v * i2; acc[0][3] += w0v * i3;
          acc[1][0] += w1v * i0; acc[1][1] += w1v * i1; acc[1][2] += w1v * i2; acc[1][3] += w1v * i3;
          acc[2][0] += w2v * i0; acc[2][1] += w2v * i1; acc[2][2] += w2v * i2; acc[2][3] += w2v * i3;
          acc[3][0] += w3v * i0; acc[3][1] += w3v * i1; acc[3][2] += w3v * i2; acc[3][3] += w3v * i3;
        }
      }
    }
    __syncthreads();
  }
  const size_t outB = (size_t)b * Co * H * W;
  #pragma unroll
  for (int i = 0; i < 4; ++i) {
    const int co = co0 + cog * 4 + i;
    const float bv = bs[co];
    float4 r;
    r.x = acc[i][0] + bv; r.y = acc[i][1] + bv; r.z = acc[i][2] + bv; r.w = acc[i][3] + bv;
    *(float4*)&out[outB + (size_t)co * H * W + (h0 + prow) * W + (w0 + pcol)] = r;
  }
}

__global__ __launch_bounds__(256) void k_xbar(const float* __restrict__ x,
                                              float* __restrict__ xbar) {
  int idx = blockIdx.x * 256 + threadIdx.x;
  if (idx >= 12288) return;
  const float* p = x + (size_t)idx * 64;
  float s = 0.f;
  #pragma unroll
  for (int t = 0; t < 64; ++t) s += p[t];
  xbar[idx] = s * 0.015625f;
}

__global__ __launch_bounds__(256) void k_pool_u8(const uint8_t* __restrict__ in,
                                                 float* __restrict__ out,
                                                 int H, int total) {
  int idx = blockIdx.x * 256 + threadIdx.x;
  if (idx >= total) return;
  int Wo = H >> 1;
  int wo = idx % Wo;
  int t1 = idx / Wo;
  int ho = t1 % Wo;
  int bc = t1 / Wo;
  size_t base = ((size_t)bc * H + 2 * ho) * H + 2 * wo;
  out[idx] = 0.25f * ((float)in[base] + (float)in[base + 1] +
                      (float)in[base + H] + (float)in[base + H + 1]);
}

__global__ __launch_bounds__(256) void k_pool_f32(const float* __restrict__ in,
                                                  float* __restrict__ out,
                                                  int H, int total) {
  int idx = blockIdx.x * 256 + threadIdx.x;
  if (idx >= total) return;
  int Wo = H >> 1;
  int wo = idx % Wo;
  int t1 = idx / Wo;
  int ho = t1 % Wo;
  int bc = t1 / Wo;
  size_t base = ((size_t)bc * H + 2 * ho) * H + 2 * wo;
  out[idx] = 0.25f * (in[base] + in[base + 1] + in[base + H] + in[base + H + 1]);
}

// Integrate-and-fire; blockIdx.y = image within this chunk (64 t-slices each).
__global__ __launch_bounds__(256) void k_if(const float* __restrict__ X,
                                            uint8_t* __restrict__ Sp,
                                            const float* __restrict__ th,
                                            float* __restrict__ ssum,
                                            int C, int HW) {
  const int CHW = C * HW;
  int idx = blockIdx.x * 256 + threadIdx.x;
  if (idx >= CHW) return;
  int c = idx / HW;
  const float thv = th[c];
  const float* p = X + (size_t)blockIdx.y * 64 * CHW + idx;
  uint8_t* q = Sp + (size_t)blockIdx.y * 64 * CHW + idx;
  float v = 0.f, ss = 0.f;
  #pragma unroll
  for (int t = 0; t < 64; ++t) {
    v += p[(size_t)t * CHW];
    float s = (v >= thv) ? 1.f : 0.f;
    v -= s * thv;
    q[(size_t)t * CHW] = (uint8_t)s;
    ss += s;
  }
  if ((HW & 63) == 0) {
    for (int off = 32; off >= 1; off >>= 1) ss += __shfl_down(ss, off);
    if ((threadIdx.x & 63) == 0) atomicAdd(&ssum[c], ss);
  } else {
    atomicAdd(&ssum[c], ss);
  }
}

__global__ __launch_bounds__(256) void k_tty(const float* __restrict__ y4,
                                             float* __restrict__ yout,
                                             float* __restrict__ ysum,
                                             int C, int HW) {
  int idx = blockIdx.x * 256 + threadIdx.x;
  if (idx >= 4 * C * HW) return;
  int rem = idx % (C * HW);
  int c = rem / HW;
  float v = floorf(y4[idx] * 64.f) * 0.015625f;
  v = fminf(fmaxf(v, 0.f), 1.f);
  yout[idx] = v;
  if ((HW & 63) == 0) {
    for (int off = 32; off >= 1; off >>= 1) v += __shfl_down(v, off);
    if ((threadIdx.x & 63) == 0) atomicAdd(&ysum[c], v);
  } else {
    atomicAdd(&ysum[c], v);
  }
}

__global__ void k_thr(const float* __restrict__ thin,
                      const float* __restrict__ ssum,
                      const float* __restrict__ ysum,
                      float* __restrict__ dst, int C, float invmul) {
  int c = blockIdx.x * 256 + threadIdx.x;
  if (c >= C) return;
  float diff = (ysum[c] * 64.f - ssum[c]) * invmul;
  dst[c] = thin[c] - 0.1f * diff;
}

__global__ void k_sumspk(const uint8_t* __restrict__ A, float* __restrict__ S) {
  int idx = blockIdx.x * 256 + threadIdx.x;
  if (idx >= 4096) return;
  int n = idx >> 10, c = idx & 1023;
  const uint8_t* p = A + (size_t)n * 64 * 1024 + c;
  float s = 0.f;
  #pragma unroll
  for (int t = 0; t < 64; ++t) s += (float)p[t * 1024];
  S[idx] = s;
}

__global__ void k_cls(const float* __restrict__ S, const float* __restrict__ wc,
                      const float* __restrict__ bcp, float* __restrict__ out) {
  int idx = blockIdx.x * 256 + threadIdx.x;
  if (idx >= 400) return;
  int n = idx / 100, o = idx - (idx / 100) * 100;
  const float* sp = S + n * 1024;
  const float* wp = wc + o * 1024;
  float acc = 0.f;
  for (int c = 0; c < 1024; ++c) acc += wp[c] * sp[c];
  out[idx] = acc * 0.015625f + bcp[o];
}

extern "C" void kernel_launch(void* const* d_in, const int* in_sizes, int n_in,
                              void* d_out_v, int out_size, void* d_ws, size_t ws_size,
                              hipStream_t stream) {
  const float *Ws[7], *Bs[7], *Wa[7], *Ba[7];
  for (int i = 0; i < 7; ++i) {
    Ws[i] = (const float*)d_in[i * 4 + 0];
    Bs[i] = (const float*)d_in[i * 4 + 1];
    Wa[i] = (const float*)d_in[i * 4 + 2];
    Ba[i] = (const float*)d_in[i * 4 + 3];
  }
  const float* wc = (const float*)d_in[28];
  const float* bc = (const float*)d_in[29];
  const float* x  = (const float*)d_in[30];
  const float* TH[7];
  for (int i = 0; i < 7; ++i) TH[i] = (const float*)d_in[31 + i];
  const float* P[4];
  for (int i = 0; i < 4; ++i) P[i] = (const float*)d_in[38 + i];
  float* out = (float*)d_out_v;

  // ---- workspace ----
  // R region (8,536,064 f): [WT (bf16 frags) | CF (f32 conv staging)]; CF
  // offset = Co*Ci*9 floats for the active layer (WT bytes = Co*Ci*36).
  float* w = (float*)d_ws;
  const size_t RF = 8536064;
  float* Rb = w;
  size_t off = RF;
  float* xbar = w + off; off += 12288;
  float* yA   = w + off; off += 524288;
  float* yB   = w + off; off += 524288;
  float* y4   = w + off; off += 524288;
  float* S    = w + off; off += 4096;
  float* sums = w + off; off += 11 * 2048;
  uint8_t* SA = (uint8_t*)(w + off);
  uint8_t* SB = SA + 33554432;
  size_t total_bytes = off * sizeof(float) + (size_t)2 * 33554432;
  if (ws_size < total_bytes) return;   // ~107.7 MB
  unsigned short* WT = (unsigned short*)Rb;

  hipMemsetAsync(sums, 0, 11 * 2048 * sizeof(float), stream);
  k_xbar<<<48, 256, 0, stream>>>(x, xbar);

  int stage = 0;

  // ---- L1 (VALU conv; input f32, K=27) ----
  {
    float* CF = Rb;
    float* ss = sums; float* ys = ss + 1024;
    for (int c = 0; c < 4; ++c) {
      k_conv<float><<<dim3(16, 2, 64), 256, 0, stream>>>(x, Ws[0], Bs[0], CF, 3, 128, 32, 1, c * 64);
      k_if<<<dim3(512, 1), 256, 0, stream>>>(CF, SA + (size_t)c * 64 * 131072, TH[0], ss, 128, 1024);
    }
    k_conv<float><<<dim3(16, 2, 4), 256, 0, stream>>>(xbar, Wa[0], Ba[0], y4, 3, 128, 32, 0, 0);
    k_tty<<<2048, 256, 0, stream>>>(y4, yA, ys, 128, 1024);
    k_thr<<<1, 256, 0, stream>>>(TH[0], ss, ys, out + 400, 128, 1.0f / (4.f * 1024.f * 64.f));
    ++stage;
  }

  // ---- MFMA conv layer (pad=1) ----
  auto mfma_layer = [&](const uint8_t* inS, uint8_t* outS, const float* inY, float* outY,
                        int li, int Ci, int Co, int H, int TRI, int tpi, int NIMG,
                        int chunkImgs, const float* thin, int outoff) {
    const int HW = H * H;
    const int CHWo = Co * HW;
    float* ss = sums + stage * 2048; float* ys = ss + 1024;
    float* CF = Rb + (size_t)Co * Ci * 9;
    int xgrid = ((Co / 64) * (Ci / 32) * 9 * 4 * 64 + 255) / 256;
    k_wxform<<<xgrid, 256, 0, stream>>>(Ws[li], WT, Ci, Co);
    int nchk = 256 / chunkImgs;
    int mt = (chunkImgs / NIMG) * tpi;
    for (int c = 0; c < nchk; ++c) {
      k_cmfma<uint8_t, false><<<dim3(Co / 64, mt), 512, 0, stream>>>(
          inS + (size_t)c * chunkImgs * Ci * HW, WT, Bs[li], CF,
          Ci, Co, H, TRI, tpi, NIMG, chunkImgs);
      k_if<<<dim3((CHWo + 255) / 256, chunkImgs / 64), 256, 0, stream>>>(
          CF, outS + (size_t)c * chunkImgs * CHWo, thin, ss, Co, HW);
    }
    k_wxform<<<xgrid, 256, 0, stream>>>(Wa[li], WT, Ci, Co);
    int mta = ((4 + NIMG - 1) / NIMG) * tpi;
    k_cmfma<float, false><<<dim3(Co / 64, mta), 512, 0, stream>>>(
        inY, WT, Ba[li], y4, Ci, Co, H, TRI, tpi, NIMG, 4);
    k_tty<<<(4 * CHWo + 255) / 256, 256, 0, stream>>>(y4, outY, ys, Co, HW);
    k_thr<<<(Co + 255) / 256, 256, 0, stream>>>(thin, ss, ys, out + outoff, Co,
                                                1.0f / (4.f * HW * 64.f));
    ++stage;
  };

  auto pool_stage = [&](const uint8_t* inS, uint8_t* outS, const float* inY, float* outY,
                        int C, int H, const float* pthr, int outoff) {
    const int Ho = H / 2, HWo = Ho * Ho;
    const int CHWo = C * HWo;
    float* CF = Rb;
    float* ss = sums + stage * 2048; float* ys = ss + 1024;
    int tot5 = 256 * CHWo;
    k_pool_u8<<<(tot5 + 255) / 256, 256, 0, stream>>>(inS, CF, H, tot5);
    k_if<<<dim3((CHWo + 255) / 256, 4), 256, 0, stream>>>(CF, outS, pthr, ss, C, HWo);
    int tot4 = 4 * CHWo;
    k_pool_f32<<<(tot4 + 255) / 256, 256, 0, stream>>>(inY, y4, H, tot4);
    k_tty<<<(tot4 + 255) / 256, 256, 0, stream>>>(y4, outY, ys, C, HWo);
    k_thr<<<(C + 255) / 256, 256, 0, stream>>>(pthr, ss, ys, out + outoff, C,
                                               1.0f / (4.f * HWo * 64.f));
    ++stage;
  };

  // L2
  mfma_layer(SA, SB, yA, yB, 1, 128, 128, 32, 8, 4, 1, 64, TH[1], 528);
  // P1
  pool_stage(SB, SA, yB, yA, 128, 32, P[0], 3216);
  // L3
  mfma_layer(SA, SB, yA, yB, 2, 128, 256, 16, 16, 1, 1, 64, TH[2], 656);
  // L4
  mfma_layer(SB, SA, yB, yA, 3, 256, 256, 16, 16, 1, 1, 64, TH[3], 912);
  // P2
  pool_stage(SA, SB, yA, yB, 256, 16, P[1], 3344);
  // L5
  mfma_layer(SB, SA, yB, yA, 4, 256, 512, 8, 8, 1, 4, 128, TH[4], 1168);
  // L6
  mfma_layer(SA, SB, yA, yB, 5, 512, 512, 8, 8, 1, 4, 128, TH[5], 1680);
  // P3
  pool_stage(SB, SA, yB, yA, 512, 8, P[2], 3600);
  // L7 (pad=0)
  {
    float* ss = sums + stage * 2048; float* ys = ss + 1024;
    float* CF = Rb + (size_t)1024 * 512 * 9;
    int xgrid = (16 * 16 * 9 * 4 * 64 + 255) / 256;
    k_wxform<<<xgrid, 256, 0, stream>>>(Ws[6], WT, 512, 1024);
    k_cmfma<uint8_t, true><<<dim3(16, 4), 512, 0, stream>>>(
        SA, WT, Bs[6], CF, 512, 1024, 4, 0, 1, 64, 256);
    k_if<<<dim3(16, 4), 256, 0, stream>>>(CF, SB, TH[6], ss, 1024, 4);
    k_wxform<<<xgrid, 256, 0, stream>>>(Wa[6], WT, 512, 1024);
    k_cmfma<float, true><<<dim3(16, 1), 512, 0, stream>>>(
        yA, WT, Ba[6], y4, 512, 1024, 4, 0, 1, 64, 4);
    k_tty<<<64, 256, 0, stream>>>(y4, yB, ys, 1024, 4);
    k_thr<<<4, 256, 0, stream>>>(TH[6], ss, ys, out + 2192, 1024, 1.0f / 1024.f);
    ++stage;
  }
  // P4
  pool_stage(SB, SA, yB, yA, 1024, 2, P[3], 4112);
  // classifier
  k_sumspk<<<16, 256, 0, stream>>>(SA, S);
  k_cls<<<2, 256, 0, stream>>>(S, wc, bc, out);
}

// Round 7
// 2812.797 us; speedup vs baseline: 4.4150x; 1.3378x over previous
//
#include <hip/hip_runtime.h>
#include <cstdint>
#include <cstddef>

// ---------------------------------------------------------------------------
// SNN "CatNet" forward, MFMA v2.
// Spiking tensors: uint8 [(n*64+t), C, H, W] (exact 0/1).
// All convs (incl. L1) run as bf16 MFMA implicit-GEMM with hi/lo split
// weights; spike/quantized inputs are exact in bf16. L1 additionally splits
// the (non-exact) input into hi/lo and uses 3 MFMAs per fragment.
// Weights: per-lane fragment layout in global (k_wxform), loaded straight
// to VGPRs per tap (double-buffered). Pixels: LDS, stride-40-short rows
// (conflict-free for b128), packed short8 writes, idiv-free staging.
// ---------------------------------------------------------------------------

typedef short short8 __attribute__((ext_vector_type(8)));   // 8 bf16
typedef float floatx4 __attribute__((ext_vector_type(4)));

__device__ __forceinline__ unsigned short f2bf_rne(float f) {
  unsigned u = __float_as_uint(f);
  return (unsigned short)((u + 0x7FFFu + ((u >> 16) & 1u)) >> 16);
}
__device__ __forceinline__ float bf2f(unsigned short h) {
  return __uint_as_float((unsigned)h << 16);
}

// ---------------------------------------------------------------------------
// Weight pre-transform (3x3 layers): W f32 [Co][Ci][3][3] -> bf16 hi/lo frags.
// frag(cot,ch,tap,cg,h) at shorts: (cot*nch+ch)*36864 + tap*4096 + cg*1024
//                                  + h*512 + lane*8
// ---------------------------------------------------------------------------
__global__ __launch_bounds__(256) void k_wxform(const float* __restrict__ Wsrc,
                                                unsigned short* __restrict__ wt,
                                                int Ci, int Co) {
  const int nch = Ci >> 5;
  const int total = (Co >> 6) * nch * 9 * 4 * 64;
  int idx = blockIdx.x * 256 + threadIdx.x;
  if (idx >= total) return;
  int lane = idx & 63;
  int t2 = idx >> 6;
  int cg = t2 & 3;
  int t3 = t2 >> 2;
  int tap = t3 % 9;
  int t4 = t3 / 9;
  int ch = t4 % nch;
  int cot = t4 / nch;
  int co = cot * 64 + cg * 16 + (lane & 15);
  int cib = ch * 32 + (lane >> 4) * 8;
  short8 vh, vl;
  #pragma unroll
  for (int j = 0; j < 8; ++j) {
    float wv = Wsrc[((size_t)co * Ci + cib + j) * 9 + tap];
    unsigned short h = f2bf_rne(wv);
    vh[j] = (short)h;
    vl[j] = (short)f2bf_rne(wv - bf2f(h));
  }
  size_t base = ((((size_t)cot * nch + ch) * 9 + tap) * 4 + cg) * 1024 + (size_t)lane * 8;
  *(short8*)&wt[base] = vh;
  *(short8*)&wt[base + 512] = vl;
}

// L1 weight transform: W f32 [128][3][3][3] -> K=32 frags, k = tap*3+ci.
// frag(cot,cg,h) at shorts: cot*4096 + cg*1024 + h*512 + lane*8
__global__ __launch_bounds__(256) void k_wxform1(const float* __restrict__ Wsrc,
                                                 unsigned short* __restrict__ wt) {
  int idx = blockIdx.x * 256 + threadIdx.x;   // 512 total
  if (idx >= 512) return;
  int lane = idx & 63, cg = (idx >> 6) & 3, cot = idx >> 8;
  int co = cot * 64 + cg * 16 + (lane & 15);
  short8 vh, vl;
  #pragma unroll
  for (int e = 0; e < 8; ++e) {
    int k = (lane >> 4) * 8 + e;
    float wv = 0.f;
    if (k < 27) { int tap = k / 3, ci = k - 3 * tap; wv = Wsrc[(co * 3 + ci) * 9 + tap]; }
    unsigned short h = f2bf_rne(wv);
    vh[e] = (short)h;
    vl[e] = (short)f2bf_rne(wv - bf2f(h));
  }
  size_t base = (size_t)cot * 4096 + cg * 1024 + (size_t)lane * 8;
  *(short8*)&wt[base] = vh;
  *(short8*)&wt[base + 512] = vl;
}

// Transpose+pack x: [n][c][hw][t] f32 -> XT2[(n*64+t)][c][hw] u32 = hi|lo<<16
__global__ __launch_bounds__(256) void k_tpack(const float* __restrict__ x,
                                               unsigned* __restrict__ XT2) {
  int idx = blockIdx.x * 256 + threadIdx.x;   // 786432
  int b = idx / 3072;
  int rem = idx - b * 3072;
  int t = b & 63, n = b >> 6;
  float f = x[((size_t)(n * 3072 + rem)) * 64 + t];
  unsigned short h = f2bf_rne(f);
  unsigned short l = f2bf_rne(f - bf2f(h));
  XT2[idx] = (unsigned)h | ((unsigned)l << 16);
}

// xbar = sum_t x / 64, packed hi/lo
__global__ __launch_bounds__(256) void k_xbar_pack(const float* __restrict__ x,
                                                   unsigned* __restrict__ xb) {
  int idx = blockIdx.x * 256 + threadIdx.x;   // 12288
  if (idx >= 12288) return;
  const float* p = x + (size_t)idx * 64;
  float s = 0.f;
  #pragma unroll
  for (int t = 0; t < 64; ++t) s += p[t];
  s *= 0.015625f;
  unsigned short h = f2bf_rne(s);
  unsigned short l = f2bf_rne(s - bf2f(h));
  xb[idx] = (unsigned)h | ((unsigned)l << 16);
}

// ---------------------------------------------------------------------------
// MFMA conv, generic 3x3. PAD0=false: pad=1 square W; PAD0=true: L7 (4x4->2x2).
// Block: 256 thr / 4 waves; wave-tile 64co x (G*16)px. A from global (per-tap
// double buffer), B from LDS (stride 40 shorts, conflict-free).
// grid.z = K-split: chunks [z*nchPer, (z+1)*nchPer), out += z*osplit,
// bias added only by z==0.
// ---------------------------------------------------------------------------
template <typename T, bool PAD0, int G>
__global__ __launch_bounds__(256) void k_cmfma(
    const T* __restrict__ in, const unsigned short* __restrict__ wt,
    const float* __restrict__ bs, float* __restrict__ out,
    int Ci, int Co, int W, int TRI, int tpi, int NIMG, int nImgValid,
    int nchPer, size_t osplit) {
  constexpr int MT = 4 * G * 16;             // block m-tile
  constexpr int PPXMAX = PAD0 ? (MT / 4) * 16 : 400;
  __shared__ unsigned short sIn[PPXMAX * 40];
  const int tid = threadIdx.x;
  const int lane = tid & 63;
  const int wv = tid >> 6;
  const int cot = blockIdx.x;
  const int mtile = blockIdx.y;
  const int kz = blockIdx.z;
  const int nch = Ci >> 5;
  const int nchA = kz * nchPer, nchB = nchA + nchPer;
  out += (size_t)kz * osplit;
  const int addBias = (kz == 0);

  int img_first, r0 = 0, PPR, PPX;
  if constexpr (PAD0) {
    img_first = mtile * (MT / 4);
    PPR = 16; PPX = (MT / 4) * 16;
  } else {
    img_first = (mtile / tpi) * NIMG;
    r0 = (mtile % tpi) * TRI;
    PPR = (TRI + 2) * (W + 2);
    PPX = NIMG * PPR;
  }
  const int TRW = TRI * W;

  // output / B-fragment mapping
  int p0[G], mimg[G], mopx[G];
  #pragma unroll
  for (int g = 0; g < G; ++g) {
    int m = wv * (G * 16) + g * 16 + (lane & 15);
    int limg;
    if constexpr (PAD0) {
      limg = m >> 2;
      int o = m & 3;
      p0[g] = limg * 16 + (o >> 1) * 4 + (o & 1);
      mopx[g] = (o >> 1) * 2 + (o & 1);
    } else {
      limg = m / TRW;
      int rm = m - limg * TRW;
      int r = rm / W, c = rm - r * W;
      p0[g] = limg * PPR + r * (W + 2) + c;
      mopx[g] = (r0 + r) * W + c;
    }
    mimg[g] = img_first + limg;
  }
  int psh[9];
  #pragma unroll
  for (int t = 0; t < 9; ++t) {
    int dh = t / 3, dw = t - dh * 3;
    psh[t] = PAD0 ? (dh * 4 + dw) : (dh * (W + 2) + dw);
  }

  // staging precompute (<=2 px per thread), idiv only here
  const int HWin = PAD0 ? 16 : W * W;
  int sgofs[2]; bool svalid[2];
  #pragma unroll
  for (int i = 0; i < 2; ++i) {
    int p = tid + i * 256;
    svalid[i] = false; sgofs[i] = 0;
    if (p < PPX) {
      int limg, gpx;
      if constexpr (PAD0) {
        limg = p >> 4; gpx = p & 15;
      } else {
        limg = p / PPR;
        int rem = p - limg * PPR;
        int pr = rem / (W + 2), pc = rem - pr * (W + 2);
        int gr = r0 + pr - 1, gc = pc - 1;
        gpx = (gr >= 0 && gr < W && gc >= 0 && gc < W) ? gr * W + gc : -1;
      }
      int img = img_first + limg;
      if (gpx >= 0 && img < nImgValid) {
        svalid[i] = true;
        sgofs[i] = img * Ci * HWin + gpx;
      }
    }
  }
  const int kb = (lane >> 4) * 8;

  floatx4 acc[4][G];
  floatx4 zero = {0.f, 0.f, 0.f, 0.f};
  #pragma unroll
  for (int cg = 0; cg < 4; ++cg)
    #pragma unroll
    for (int g = 0; g < G; ++g) acc[cg][g] = zero;

  for (int ch = nchA; ch < nchB; ++ch) {
    const int ci0 = ch * 32;
    // ---- stage input patch [px][32 ci] as bf16, packed b128 writes ----
    #pragma unroll
    for (int i = 0; i < 2; ++i) {
      int p = tid + i * 256;
      if (p < PPX) {
        unsigned short* dst = &sIn[p * 40];
        if (svalid[i]) {
          const T* sp = in + sgofs[i] + (size_t)ci0 * HWin;
          #pragma unroll
          for (int j = 0; j < 4; ++j) {
            short8 v;
            #pragma unroll
            for (int e = 0; e < 8; ++e) {
              if constexpr (sizeof(T) == 1)
                v[e] = sp[(size_t)(j * 8 + e) * HWin] ? (short)0x3F80 : (short)0;
              else
                v[e] = (short)f2bf_rne(((const float*)sp)[(size_t)(j * 8 + e) * HWin]);
            }
            *(short8*)&dst[j * 8] = v;
          }
        } else {
          short8 z = {};
          #pragma unroll
          for (int j = 0; j < 4; ++j) *(short8*)&dst[j * 8] = z;
        }
      }
    }
    __syncthreads();
    // ---- taps: A from global (double-buffered), B from LDS ----
    const unsigned short* wb = wt + ((size_t)(cot * nch + ch)) * 36864 + (size_t)lane * 8;
    short8 A[2][8];
    #pragma unroll
    for (int f = 0; f < 8; ++f)
      A[0][f] = *(const short8*)(wb + (f >> 1) * 1024 + (f & 1) * 512);
    #pragma unroll
    for (int t = 0; t < 9; ++t) {
      const int cur = t & 1;
      if (t < 8) {
        #pragma unroll
        for (int f = 0; f < 8; ++f)
          A[cur ^ 1][f] = *(const short8*)(wb + (size_t)(t + 1) * 4096 + (f >> 1) * 1024 + (f & 1) * 512);
      }
      short8 b[G];
      #pragma unroll
      for (int g = 0; g < G; ++g)
        b[g] = *(const short8*)&sIn[(p0[g] + psh[t]) * 40 + kb];
      #pragma unroll
      for (int cg = 0; cg < 4; ++cg) {
        #pragma unroll
        for (int g = 0; g < G; ++g) {
          acc[cg][g] = __builtin_amdgcn_mfma_f32_16x16x32_bf16(A[cur][cg * 2 + 0], b[g], acc[cg][g], 0, 0, 0);
          acc[cg][g] = __builtin_amdgcn_mfma_f32_16x16x32_bf16(A[cur][cg * 2 + 1], b[g], acc[cg][g], 0, 0, 0);
        }
      }
    }
    __syncthreads();
  }
  // ---- epilogue: row=(lane>>4)*4+i -> co, col=lane&15 -> px ----
  const int HWout = PAD0 ? 4 : W * W;
  #pragma unroll
  for (int g = 0; g < G; ++g) {
    if (mimg[g] >= nImgValid) continue;
    #pragma unroll
    for (int cg = 0; cg < 4; ++cg) {
      #pragma unroll
      for (int i2 = 0; i2 < 4; ++i2) {
        int co = cot * 64 + cg * 16 + (lane >> 4) * 4 + i2;
        float bv = addBias ? bs[co] : 0.f;
        out[((size_t)mimg[g] * Co + co) * HWout + mopx[g]] = acc[cg][g][i2] + bv;
      }
    }
  }
}

// ---------------------------------------------------------------------------
// L1 MFMA conv: K=32 im2col (k=tap*3+ci, pad 27..31), input packed hi/lo u32.
// Input xin [img][3][1024]; block = 64co x 256px (one img, 8 rows).
// 3 MFMAs: Whi*Xhi + Whi*Xlo + Wlo*Xhi.
// ---------------------------------------------------------------------------
__global__ __launch_bounds__(256) void k_l1(const unsigned* __restrict__ xin,
                                            const unsigned short* __restrict__ wt,
                                            const float* __restrict__ bs,
                                            float* __restrict__ out,
                                            int nImgValid) {
  __shared__ unsigned short sIn[256 * 72];   // [m][hi(32) | lo(32)], stride 72
  const int tid = threadIdx.x, lane = tid & 63, wv = tid >> 6;
  const int cot = blockIdx.x, mtile = blockIdx.y;
  const int img = mtile >> 2;
  const int r0 = (mtile & 3) * 8;
  // stage: one out-px per thread
  {
    int m = tid;
    int r = r0 + (m >> 5), c = m & 31;
    const unsigned* ip = xin + (size_t)img * 3072;
    unsigned v[9][3];
    bool iv = (img < nImgValid);
    #pragma unroll
    for (int dh = 0; dh < 3; ++dh) {
      #pragma unroll
      for (int dw = 0; dw < 3; ++dw) {
        int rr = r + dh - 1, cc = c + dw - 1;
        bool ok = iv && rr >= 0 && rr < 32 && cc >= 0 && cc < 32;
        #pragma unroll
        for (int ci = 0; ci < 3; ++ci)
          v[dh * 3 + dw][ci] = ok ? ip[ci * 1024 + rr * 32 + cc] : 0u;
      }
    }
    #pragma unroll
    for (int j = 0; j < 4; ++j) {
      short8 vh, vl;
      #pragma unroll
      for (int e = 0; e < 8; ++e) {
        int k = j * 8 + e;
        unsigned u = (k < 27) ? v[k / 3][k - 3 * (k / 3)] : 0u;
        vh[e] = (short)(u & 0xFFFFu);
        vl[e] = (short)(u >> 16);
      }
      *(short8*)&sIn[m * 72 + j * 8] = vh;
      *(short8*)&sIn[m * 72 + 32 + j * 8] = vl;
    }
  }
  __syncthreads();
  const int kb = (lane >> 4) * 8;
  const unsigned short* wb = wt + (size_t)cot * 4096 + (size_t)lane * 8;
  short8 Af[8];
  #pragma unroll
  for (int f = 0; f < 8; ++f)
    Af[f] = *(const short8*)(wb + (f >> 1) * 1024 + (f & 1) * 512);
  floatx4 acc[4][4];
  floatx4 zero = {0.f, 0.f, 0.f, 0.f};
  #pragma unroll
  for (int cg = 0; cg < 4; ++cg)
    #pragma unroll
    for (int g = 0; g < 4; ++g) acc[cg][g] = zero;
  short8 bh[4], bl[4];
  #pragma unroll
  for (int g = 0; g < 4; ++g) {
    int m = wv * 64 + g * 16 + (lane & 15);
    bh[g] = *(const short8*)&sIn[m * 72 + kb];
    bl[g] = *(const short8*)&sIn[m * 72 + 32 + kb];
  }
  #pragma unroll
  for (int cg = 0; cg < 4; ++cg) {
    #pragma unroll
    for (int g = 0; g < 4; ++g) {
      acc[cg][g] = __builtin_amdgcn_mfma_f32_16x16x32_bf16(Af[cg * 2 + 0], bh[g], acc[cg][g], 0, 0, 0);
      acc[cg][g] = __builtin_amdgcn_mfma_f32_16x16x32_bf16(Af[cg * 2 + 0], bl[g], acc[cg][g], 0, 0, 0);
      acc[cg][g] = __builtin_amdgcn_mfma_f32_16x16x32_bf16(Af[cg * 2 + 1], bh[g], acc[cg][g], 0, 0, 0);
    }
  }
  if (img >= nImgValid) return;
  #pragma unroll
  for (int g = 0; g < 4; ++g) {
    int mbase = wv * 64 + g * 16 + (lane & 15);
    int px = (r0 + (mbase >> 5)) * 32 + (mbase & 31);
    #pragma unroll
    for (int cg = 0; cg < 4; ++cg) {
      #pragma unroll
      for (int i2 = 0; i2 < 4; ++i2) {
        int co = cot * 64 + cg * 16 + (lane >> 4) * 4 + i2;
        out[((size_t)img * 128 + co) * 1024 + px] = acc[cg][g][i2] + bs[co];
      }
    }
  }
}

// ---------------------------------------------------------------------------
__global__ __launch_bounds__(256) void k_pool_u8(const uint8_t* __restrict__ in,
                                                 float* __restrict__ out,
                                                 int H, int total) {
  int idx = blockIdx.x * 256 + threadIdx.x;
  if (idx >= total) return;
  int Wo = H >> 1;
  int wo = idx % Wo;
  int t1 = idx / Wo;
  int ho = t1 % Wo;
  int bc = t1 / Wo;
  size_t base = ((size_t)bc * H + 2 * ho) * H + 2 * wo;
  out[idx] = 0.25f * ((float)in[base] + (float)in[base + 1] +
                      (float)in[base + H] + (float)in[base + H + 1]);
}

__global__ __launch_bounds__(256) void k_pool_f32(const float* __restrict__ in,
                                                  float* __restrict__ out,
                                                  int H, int total) {
  int idx = blockIdx.x * 256 + threadIdx.x;
  if (idx >= total) return;
  int Wo = H >> 1;
  int wo = idx % Wo;
  int t1 = idx / Wo;
  int ho = t1 % Wo;
  int bc = t1 / Wo;
  size_t base = ((size_t)bc * H + 2 * ho) * H + 2 * wo;
  out[idx] = 0.25f * (in[base] + in[base + 1] + in[base + H] + in[base + H + 1]);
}

// Integrate-and-fire; blockIdx.y = 64-t group. Optional second partial Xb.
__global__ __launch_bounds__(256) void k_if(const float* __restrict__ X,
                                            const float* __restrict__ Xb,
                                            uint8_t* __restrict__ Sp,
                                            const float* __restrict__ th,
                                            float* __restrict__ ssum,
                                            int C, int HW) {
  const int CHW = C * HW;
  int idx = blockIdx.x * 256 + threadIdx.x;
  if (idx >= CHW) return;
  int c = idx / HW;
  const float thv = th[c];
  size_t base = (size_t)blockIdx.y * 64 * CHW + idx;
  const float* p = X + base;
  const float* pb = Xb ? (Xb + base) : nullptr;
  uint8_t* q = Sp + base;
  float v = 0.f, ss = 0.f;
  #pragma unroll
  for (int t = 0; t < 64; ++t) {
    float xv = p[(size_t)t * CHW];
    if (pb) xv += pb[(size_t)t * CHW];
    v += xv;
    float s = (v >= thv) ? 1.f : 0.f;
    v -= s * thv;
    q[(size_t)t * CHW] = (uint8_t)s;
    ss += s;
  }
  if ((HW & 63) == 0) {
    for (int off = 32; off >= 1; off >>= 1) ss += __shfl_down(ss, off);
    if ((threadIdx.x & 63) == 0) atomicAdd(&ssum[c], ss);
  } else {
    atomicAdd(&ssum[c], ss);
  }
}

__global__ __launch_bounds__(256) void k_tty(const float* __restrict__ y4,
                                             float* __restrict__ yout,
                                             float* __restrict__ ysum,
                                             int C, int HW) {
  int idx = blockIdx.x * 256 + threadIdx.x;
  if (idx >= 4 * C * HW) return;
  int rem = idx % (C * HW);
  int c = rem / HW;
  float v = floorf(y4[idx] * 64.f) * 0.015625f;
  v = fminf(fmaxf(v, 0.f), 1.f);
  yout[idx] = v;
  if ((HW & 63) == 0) {
    for (int off = 32; off >= 1; off >>= 1) v += __shfl_down(v, off);
    if ((threadIdx.x & 63) == 0) atomicAdd(&ysum[c], v);
  } else {
    atomicAdd(&ysum[c], v);
  }
}

__global__ void k_thr(const float* __restrict__ thin,
                      const float* __restrict__ ssum,
                      const float* __restrict__ ysum,
                      float* __restrict__ dst, int C, float invmul) {
  int c = blockIdx.x * 256 + threadIdx.x;
  if (c >= C) return;
  float diff = (ysum[c] * 64.f - ssum[c]) * invmul;
  dst[c] = thin[c] - 0.1f * diff;
}

__global__ void k_sumspk(const uint8_t* __restrict__ A, float* __restrict__ S) {
  int idx = blockIdx.x * 256 + threadIdx.x;
  if (idx >= 4096) return;
  int n = idx >> 10, c = idx & 1023;
  const uint8_t* p = A + (size_t)n * 64 * 1024 + c;
  float s = 0.f;
  #pragma unroll
  for (int t = 0; t < 64; ++t) s += (float)p[t * 1024];
  S[idx] = s;
}

__global__ void k_cls(const float* __restrict__ S, const float* __restrict__ wc,
                      const float* __restrict__ bcp, float* __restrict__ out) {
  int idx = blockIdx.x * 256 + threadIdx.x;
  if (idx >= 400) return;
  int n = idx / 100, o = idx - (idx / 100) * 100;
  const float* sp = S + n * 1024;
  const float* wp = wc + o * 1024;
  float acc = 0.f;
  for (int c = 0; c < 1024; ++c) acc += wp[c] * sp[c];
  out[idx] = acc * 0.015625f + bcp[o];
}

extern "C" void kernel_launch(void* const* d_in, const int* in_sizes, int n_in,
                              void* d_out_v, int out_size, void* d_ws, size_t ws_size,
                              hipStream_t stream) {
  const float *Ws[7], *Bs[7], *Wa[7], *Ba[7];
  for (int i = 0; i < 7; ++i) {
    Ws[i] = (const float*)d_in[i * 4 + 0];
    Bs[i] = (const float*)d_in[i * 4 + 1];
    Wa[i] = (const float*)d_in[i * 4 + 2];
    Ba[i] = (const float*)d_in[i * 4 + 3];
  }
  const float* wc = (const float*)d_in[28];
  const float* bc = (const float*)d_in[29];
  const float* x  = (const float*)d_in[30];
  const float* TH[7];
  for (int i = 0; i < 7; ++i) TH[i] = (const float*)d_in[31 + i];
  const float* P[4];
  for (int i = 0; i < 4; ++i) P[i] = (const float*)d_in[38 + i];
  float* out = (float*)d_out_v;

  // ---- workspace (same 107.7 MB footprint as round 6) ----
  float* w = (float*)d_ws;
  const size_t RF = 8536064;      // [WT | CF] region, per-layer split
  float* Rb = w;
  size_t off = RF;
  float* xbar = w + off; off += 12288;    // packed u32 hi/lo
  float* yA   = w + off; off += 524288;
  float* yB   = w + off; off += 524288;
  float* y4   = w + off; off += 524288;
  float* S    = w + off; off += 4096;
  float* sums = w + off; off += 11 * 2048;
  uint8_t* SA = (uint8_t*)(w + off);
  uint8_t* SB = SA + 33554432;
  size_t total_bytes = off * sizeof(float) + (size_t)2 * 33554432;
  if (ws_size < total_bytes) return;
  unsigned short* WT = (unsigned short*)Rb;
  unsigned* XT2 = (unsigned*)SB;          // aliases SB (dead until L2 output)
  unsigned* xbar2 = (unsigned*)xbar;

  hipMemsetAsync(sums, 0, 11 * 2048 * sizeof(float), stream);
  k_tpack<<<3072, 256, 0, stream>>>(x, XT2);
  k_xbar_pack<<<48, 256, 0, stream>>>(x, xbar2);

  int stage = 0;

  // ---- L1 (MFMA im2col) ----
  {
    float* CF = Rb + 4096;                 // WT1 = 16 KB
    float* ss = sums; float* ys = ss + 1024;
    k_wxform1<<<2, 256, 0, stream>>>(Ws[0], WT);
    for (int c = 0; c < 4; ++c) {
      k_l1<<<dim3(2, 256), 256, 0, stream>>>(XT2 + (size_t)c * 64 * 3072, WT, Bs[0], CF, 64);
      k_if<<<dim3(512, 1), 256, 0, stream>>>(CF, nullptr, SA + (size_t)c * 64 * 131072,
                                             TH[0], ss, 128, 1024);
    }
    k_wxform1<<<2, 256, 0, stream>>>(Wa[0], WT);
    k_l1<<<dim3(2, 16), 256, 0, stream>>>(xbar2, WT, Ba[0], y4, 4);
    k_tty<<<2048, 256, 0, stream>>>(y4, yA, ys, 128, 1024);
    k_thr<<<1, 256, 0, stream>>>(TH[0], ss, ys, out + 400, 128, 1.0f / (4.f * 1024.f * 64.f));
    ++stage;
  }

  // ---- generic pad=1 MFMA layer ----
  auto mfma_layer = [&](const uint8_t* inS, uint8_t* outS, const float* inY, float* outY,
                        int li, int Ci, int Co, int W, int TRI, int tpi, int NIMG,
                        int chunkImgs, const float* thin, int outoff) {
    const int HW = W * W;
    const int CHWo = Co * HW;
    const int nch = Ci >> 5;
    float* ss = sums + stage * 2048; float* ys = ss + 1024;
    float* CF = Rb + (size_t)Co * Ci * 9;
    int xgrid = ((Co / 64) * nch * 9 * 4 * 64 + 255) / 256;
    k_wxform<<<xgrid, 256, 0, stream>>>(Ws[li], WT, Ci, Co);
    int nchk = 256 / chunkImgs;
    int mt = (chunkImgs / NIMG) * tpi;
    for (int c = 0; c < nchk; ++c) {
      k_cmfma<uint8_t, false, 4><<<dim3(Co / 64, mt, 1), 256, 0, stream>>>(
          inS + (size_t)c * chunkImgs * Ci * HW, WT, Bs[li], CF,
          Ci, Co, W, TRI, tpi, NIMG, chunkImgs, nch, 0);
      k_if<<<dim3((CHWo + 255) / 256, chunkImgs / 64), 256, 0, stream>>>(
          CF, nullptr, outS + (size_t)c * chunkImgs * CHWo, thin, ss, Co, HW);
    }
    k_wxform<<<xgrid, 256, 0, stream>>>(Wa[li], WT, Ci, Co);
    int mta = ((4 + NIMG - 1) / NIMG) * tpi;
    k_cmfma<float, false, 4><<<dim3(Co / 64, mta, 1), 256, 0, stream>>>(
        inY, WT, Ba[li], y4, Ci, Co, W, TRI, tpi, NIMG, 4, nch, 0);
    k_tty<<<(4 * CHWo + 255) / 256, 256, 0, stream>>>(y4, outY, ys, Co, HW);
    k_thr<<<(Co + 255) / 256, 256, 0, stream>>>(thin, ss, ys, out + outoff, Co,
                                                1.0f / (4.f * HW * 64.f));
    ++stage;
  };

  auto pool_stage = [&](const uint8_t* inS, uint8_t* outS, const float* inY, float* outY,
                        int C, int H, const float* pthr, int outoff) {
    const int Ho = H / 2, HWo = Ho * Ho;
    const int CHWo = C * HWo;
    float* CF = Rb;
    float* ss = sums + stage * 2048; float* ys = ss + 1024;
    int tot5 = 256 * CHWo;
    k_pool_u8<<<(tot5 + 255) / 256, 256, 0, stream>>>(inS, CF, H, tot5);
    k_if<<<dim3((CHWo + 255) / 256, 4), 256, 0, stream>>>(CF, nullptr, outS, pthr, ss, C, HWo);
    int tot4 = 4 * CHWo;
    k_pool_f32<<<(tot4 + 255) / 256, 256, 0, stream>>>(inY, y4, H, tot4);
    k_tty<<<(tot4 + 255) / 256, 256, 0, stream>>>(y4, outY, ys, C, HWo);
    k_thr<<<(C + 255) / 256, 256, 0, stream>>>(pthr, ss, ys, out + outoff, C,
                                               1.0f / (4.f * HWo * 64.f));
    ++stage;
  };

  // L2
  mfma_layer(SA, SB, yA, yB, 1, 128, 128, 32, 8, 4, 1, 64, TH[1], 528);
  // P1
  pool_stage(SB, SA, yB, yA, 128, 32, P[0], 3216);
  // L3
  mfma_layer(SA, SB, yA, yB, 2, 128, 256, 16, 16, 1, 1, 64, TH[2], 656);
  // L4
  mfma_layer(SB, SA, yB, yA, 3, 256, 256, 16, 16, 1, 1, 64, TH[3], 912);
  // P2
  pool_stage(SA, SB, yA, yB, 256, 16, P[1], 3344);
  // L5
  mfma_layer(SB, SA, yB, yA, 4, 256, 512, 8, 8, 1, 4, 128, TH[4], 1168);
  // L6
  mfma_layer(SA, SB, yA, yB, 5, 512, 512, 8, 8, 1, 4, 128, TH[5], 1680);
  // P3
  pool_stage(SB, SA, yB, yA, 512, 8, P[2], 3600);
  // L7 (pad=0), K-split 2 with partial buffers
  {
    float* ss = sums + stage * 2048; float* ys = ss + 1024;
    float* CF = Rb + (size_t)1024 * 512 * 9;    // 4.72M floats
    const size_t osplit = 1048576;              // 256*1024*4
    int xgrid = (16 * 16 * 9 * 4 * 64 + 255) / 256;
    k_wxform<<<xgrid, 256, 0, stream>>>(Ws[6], WT, 512, 1024);
    k_cmfma<uint8_t, true, 2><<<dim3(16, 8, 2), 256, 0, stream>>>(
        SA, WT, Bs[6], CF, 512, 1024, 4, 0, 1, 0, 256, 8, osplit);
    k_if<<<dim3(16, 4), 256, 0, stream>>>(CF, CF + osplit, SB, TH[6], ss, 1024, 4);
    k_wxform<<<xgrid, 256, 0, stream>>>(Wa[6], WT, 512, 1024);
    k_cmfma<float, true, 2><<<dim3(16, 1, 1), 256, 0, stream>>>(
        yA, WT, Ba[6], y4, 512, 1024, 4, 0, 1, 0, 4, 16, 0);
    k_tty<<<64, 256, 0, stream>>>(y4, yB, ys, 1024, 4);
    k_thr<<<4, 256, 0, stream>>>(TH[6], ss, ys, out + 2192, 1024, 1.0f / 1024.f);
    ++stage;
  }
  // P4
  pool_stage(SB, SA, yB, yA, 1024, 2, P[3], 4112);
  // classifier
  k_sumspk<<<16, 256, 0, stream>>>(SA, S);
  k_cls<<<2, 256, 0, stream>>>(S, wc, bc, out);
}

// Round 8
// 2663.018 us; speedup vs baseline: 4.6634x; 1.0562x over previous
//
#include <hip/hip_runtime.h>
#include <cstdint>
#include <cstddef>

// ---------------------------------------------------------------------------
// SNN "CatNet" forward, MFMA v3.
// Spiking tensors: uint8 [(n*64+t), C, H, W] (exact 0/1).
// All convs run as bf16 MFMA implicit-GEMM with hi/lo split weights.
// v3: __launch_bounds__(256,1) (regalloc freedom), gather-then-write staging
// (single vmcnt wait), K-split x2 on L3-L6 (2 blocks/CU latency hiding).
// ---------------------------------------------------------------------------

typedef short short8 __attribute__((ext_vector_type(8)));   // 8 bf16
typedef float floatx4 __attribute__((ext_vector_type(4)));

__device__ __forceinline__ unsigned short f2bf_rne(float f) {
  unsigned u = __float_as_uint(f);
  return (unsigned short)((u + 0x7FFFu + ((u >> 16) & 1u)) >> 16);
}
__device__ __forceinline__ float bf2f(unsigned short h) {
  return __uint_as_float((unsigned)h << 16);
}

// ---------------------------------------------------------------------------
// Weight pre-transform (3x3 layers): W f32 [Co][Ci][3][3] -> bf16 hi/lo frags.
// frag(cot,ch,tap,cg,h) at shorts: (cot*nch+ch)*36864 + tap*4096 + cg*1024
//                                  + h*512 + lane*8
// ---------------------------------------------------------------------------
__global__ __launch_bounds__(256) void k_wxform(const float* __restrict__ Wsrc,
                                                unsigned short* __restrict__ wt,
                                                int Ci, int Co) {
  const int nch = Ci >> 5;
  const int total = (Co >> 6) * nch * 9 * 4 * 64;
  int idx = blockIdx.x * 256 + threadIdx.x;
  if (idx >= total) return;
  int lane = idx & 63;
  int t2 = idx >> 6;
  int cg = t2 & 3;
  int t3 = t2 >> 2;
  int tap = t3 % 9;
  int t4 = t3 / 9;
  int ch = t4 % nch;
  int cot = t4 / nch;
  int co = cot * 64 + cg * 16 + (lane & 15);
  int cib = ch * 32 + (lane >> 4) * 8;
  short8 vh, vl;
  #pragma unroll
  for (int j = 0; j < 8; ++j) {
    float wv = Wsrc[((size_t)co * Ci + cib + j) * 9 + tap];
    unsigned short h = f2bf_rne(wv);
    vh[j] = (short)h;
    vl[j] = (short)f2bf_rne(wv - bf2f(h));
  }
  size_t base = ((((size_t)cot * nch + ch) * 9 + tap) * 4 + cg) * 1024 + (size_t)lane * 8;
  *(short8*)&wt[base] = vh;
  *(short8*)&wt[base + 512] = vl;
}

// L1 weight transform: W f32 [128][3][3][3] -> K=32 frags, k = tap*3+ci.
__global__ __launch_bounds__(256) void k_wxform1(const float* __restrict__ Wsrc,
                                                 unsigned short* __restrict__ wt) {
  int idx = blockIdx.x * 256 + threadIdx.x;   // 512 total
  if (idx >= 512) return;
  int lane = idx & 63, cg = (idx >> 6) & 3, cot = idx >> 8;
  int co = cot * 64 + cg * 16 + (lane & 15);
  short8 vh, vl;
  #pragma unroll
  for (int e = 0; e < 8; ++e) {
    int k = (lane >> 4) * 8 + e;
    float wv = 0.f;
    if (k < 27) { int tap = k / 3, ci = k - 3 * tap; wv = Wsrc[(co * 3 + ci) * 9 + tap]; }
    unsigned short h = f2bf_rne(wv);
    vh[e] = (short)h;
    vl[e] = (short)f2bf_rne(wv - bf2f(h));
  }
  size_t base = (size_t)cot * 4096 + cg * 1024 + (size_t)lane * 8;
  *(short8*)&wt[base] = vh;
  *(short8*)&wt[base + 512] = vl;
}

// Transpose+pack x: [n][c][hw][t] f32 -> XT2[(n*64+t)][c][hw] u32 = hi|lo<<16
__global__ __launch_bounds__(256) void k_tpack(const float* __restrict__ x,
                                               unsigned* __restrict__ XT2) {
  int idx = blockIdx.x * 256 + threadIdx.x;   // 786432
  int b = idx / 3072;
  int rem = idx - b * 3072;
  int t = b & 63, n = b >> 6;
  float f = x[((size_t)(n * 3072 + rem)) * 64 + t];
  unsigned short h = f2bf_rne(f);
  unsigned short l = f2bf_rne(f - bf2f(h));
  XT2[idx] = (unsigned)h | ((unsigned)l << 16);
}

__global__ __launch_bounds__(256) void k_xbar_pack(const float* __restrict__ x,
                                                   unsigned* __restrict__ xb) {
  int idx = blockIdx.x * 256 + threadIdx.x;   // 12288
  if (idx >= 12288) return;
  const float* p = x + (size_t)idx * 64;
  float s = 0.f;
  #pragma unroll
  for (int t = 0; t < 64; ++t) s += p[t];
  s *= 0.015625f;
  unsigned short h = f2bf_rne(s);
  unsigned short l = f2bf_rne(s - bf2f(h));
  xb[idx] = (unsigned)h | ((unsigned)l << 16);
}

// ---------------------------------------------------------------------------
// MFMA conv, generic 3x3. PAD0=false: pad=1 square W; PAD0=true: L7 (4x4->2x2).
// Block: 256 thr / 4 waves; wave-tile 64co x (G*16)px. A from global (per-tap
// double buffer), B from LDS (stride-40-short rows, conflict-free b128).
// grid.z = K-split: chunks [z*nchPer, (z+1)*nchPer), out += z*osplit,
// bias added only by z==0.
// ---------------------------------------------------------------------------
template <typename T, bool PAD0, int G>
__global__ __launch_bounds__(256, 1) void k_cmfma(
    const T* __restrict__ in, const unsigned short* __restrict__ wt,
    const float* __restrict__ bs, float* __restrict__ out,
    int Ci, int Co, int W, int TRI, int tpi, int NIMG, int nImgValid,
    int nchPer, size_t osplit) {
  constexpr int MT = 4 * G * 16;             // block m-tile
  constexpr int PPXMAX = PAD0 ? (MT / 4) * 16 : 400;
  __shared__ unsigned short sIn[PPXMAX * 40];
  const int tid = threadIdx.x;
  const int lane = tid & 63;
  const int wv = tid >> 6;
  const int cot = blockIdx.x;
  const int mtile = blockIdx.y;
  const int kz = blockIdx.z;
  const int nch = Ci >> 5;
  const int nchA = kz * nchPer, nchB = nchA + nchPer;
  out += (size_t)kz * osplit;
  const int addBias = (kz == 0);

  int img_first, r0 = 0, PPR, PPX;
  if constexpr (PAD0) {
    img_first = mtile * (MT / 4);
    PPR = 16; PPX = (MT / 4) * 16;
  } else {
    img_first = (mtile / tpi) * NIMG;
    r0 = (mtile % tpi) * TRI;
    PPR = (TRI + 2) * (W + 2);
    PPX = NIMG * PPR;
  }
  const int TRW = TRI * W;

  // output / B-fragment mapping
  int p0[G], mimg[G], mopx[G];
  #pragma unroll
  for (int g = 0; g < G; ++g) {
    int m = wv * (G * 16) + g * 16 + (lane & 15);
    int limg;
    if constexpr (PAD0) {
      limg = m >> 2;
      int o = m & 3;
      p0[g] = limg * 16 + (o >> 1) * 4 + (o & 1);
      mopx[g] = (o >> 1) * 2 + (o & 1);
    } else {
      limg = m / TRW;
      int rm = m - limg * TRW;
      int r = rm / W, c = rm - r * W;
      p0[g] = limg * PPR + r * (W + 2) + c;
      mopx[g] = (r0 + r) * W + c;
    }
    mimg[g] = img_first + limg;
  }
  int psh[9];
  #pragma unroll
  for (int t = 0; t < 9; ++t) {
    int dh = t / 3, dw = t - dh * 3;
    psh[t] = PAD0 ? (dh * 4 + dw) : (dh * (W + 2) + dw);
  }

  // staging precompute (<=2 px per thread), idiv only here
  const int HWin = PAD0 ? 16 : W * W;
  int sgofs[2]; bool svalid[2];
  #pragma unroll
  for (int i = 0; i < 2; ++i) {
    int p = tid + i * 256;
    svalid[i] = false; sgofs[i] = 0;
    if (p < PPX) {
      int limg, gpx;
      if constexpr (PAD0) {
        limg = p >> 4; gpx = p & 15;
      } else {
        limg = p / PPR;
        int rem = p - limg * PPR;
        int pr = rem / (W + 2), pc = rem - pr * (W + 2);
        int gr = r0 + pr - 1, gc = pc - 1;
        gpx = (gr >= 0 && gr < W && gc >= 0 && gc < W) ? gr * W + gc : -1;
      }
      int img = img_first + limg;
      if (gpx >= 0 && img < nImgValid) {
        svalid[i] = true;
        sgofs[i] = img * Ci * HWin + gpx;
      }
    }
  }
  const int kb = (lane >> 4) * 8;

  floatx4 acc[4][G];
  floatx4 zero = {0.f, 0.f, 0.f, 0.f};
  #pragma unroll
  for (int cg = 0; cg < 4; ++cg)
    #pragma unroll
    for (int g = 0; g < G; ++g) acc[cg][g] = zero;

  for (int ch = nchA; ch < nchB; ++ch) {
    const int ci0 = ch * 32;
    // ---- gather all staging bytes into regs (one wait), then write LDS ----
    unsigned rawu[2][32];
    float rawf[2][32];
    #pragma unroll
    for (int i = 0; i < 2; ++i) {
      if (tid + i * 256 < PPX && svalid[i]) {
        const T* sp = in + sgofs[i] + (size_t)ci0 * HWin;
        #pragma unroll
        for (int k = 0; k < 32; ++k) {
          if constexpr (sizeof(T) == 1) rawu[i][k] = sp[(size_t)k * HWin];
          else rawf[i][k] = ((const float*)sp)[(size_t)k * HWin];
        }
      }
    }
    #pragma unroll
    for (int i = 0; i < 2; ++i) {
      int p = tid + i * 256;
      if (p < PPX) {
        unsigned short* dst = &sIn[p * 40];
        if (svalid[i]) {
          #pragma unroll
          for (int j = 0; j < 4; ++j) {
            short8 v;
            #pragma unroll
            for (int e = 0; e < 8; ++e) {
              if constexpr (sizeof(T) == 1)
                v[e] = rawu[i][j * 8 + e] ? (short)0x3F80 : (short)0;
              else
                v[e] = (short)f2bf_rne(rawf[i][j * 8 + e]);
            }
            *(short8*)&dst[j * 8] = v;
          }
        } else {
          short8 z = {};
          #pragma unroll
          for (int j = 0; j < 4; ++j) *(short8*)&dst[j * 8] = z;
        }
      }
    }
    __syncthreads();
    // ---- taps: A from global (double-buffered), B from LDS ----
    const unsigned short* wb = wt + ((size_t)(cot * nch + ch)) * 36864 + (size_t)lane * 8;
    short8 A[2][8];
    #pragma unroll
    for (int f = 0; f < 8; ++f)
      A[0][f] = *(const short8*)(wb + (f >> 1) * 1024 + (f & 1) * 512);
    #pragma unroll
    for (int t = 0; t < 9; ++t) {
      const int cur = t & 1;
      if (t < 8) {
        #pragma unroll
        for (int f = 0; f < 8; ++f)
          A[cur ^ 1][f] = *(const short8*)(wb + (size_t)(t + 1) * 4096 + (f >> 1) * 1024 + (f & 1) * 512);
      }
      short8 b[G];
      #pragma unroll
      for (int g = 0; g < G; ++g)
        b[g] = *(const short8*)&sIn[(p0[g] + psh[t]) * 40 + kb];
      #pragma unroll
      for (int cg = 0; cg < 4; ++cg) {
        #pragma unroll
        for (int g = 0; g < G; ++g) {
          acc[cg][g] = __builtin_amdgcn_mfma_f32_16x16x32_bf16(A[cur][cg * 2 + 0], b[g], acc[cg][g], 0, 0, 0);
          acc[cg][g] = __builtin_amdgcn_mfma_f32_16x16x32_bf16(A[cur][cg * 2 + 1], b[g], acc[cg][g], 0, 0, 0);
        }
      }
    }
    __syncthreads();
  }
  // ---- epilogue: row=(lane>>4)*4+i -> co, col=lane&15 -> px ----
  const int HWout = PAD0 ? 4 : W * W;
  #pragma unroll
  for (int g = 0; g < G; ++g) {
    if (mimg[g] >= nImgValid) continue;
    #pragma unroll
    for (int cg = 0; cg < 4; ++cg) {
      #pragma unroll
      for (int i2 = 0; i2 < 4; ++i2) {
        int co = cot * 64 + cg * 16 + (lane >> 4) * 4 + i2;
        float bv = addBias ? bs[co] : 0.f;
        out[((size_t)mimg[g] * Co + co) * HWout + mopx[g]] = acc[cg][g][i2] + bv;
      }
    }
  }
}

// ---------------------------------------------------------------------------
// L1 MFMA conv: K=32 im2col (k=tap*3+ci), input packed hi/lo u32.
// ---------------------------------------------------------------------------
__global__ __launch_bounds__(256, 1) void k_l1(const unsigned* __restrict__ xin,
                                               const unsigned short* __restrict__ wt,
                                               const float* __restrict__ bs,
                                               float* __restrict__ out,
                                               int nImgValid) {
  __shared__ unsigned short sIn[256 * 72];   // [m][hi(32) | lo(32)], stride 72
  const int tid = threadIdx.x, lane = tid & 63, wv = tid >> 6;
  const int cot = blockIdx.x, mtile = blockIdx.y;
  const int img = mtile >> 2;
  const int r0 = (mtile & 3) * 8;
  {
    int m = tid;
    int r = r0 + (m >> 5), c = m & 31;
    const unsigned* ip = xin + (size_t)img * 3072;
    unsigned v[9][3];
    bool iv = (img < nImgValid);
    #pragma unroll
    for (int dh = 0; dh < 3; ++dh) {
      #pragma unroll
      for (int dw = 0; dw < 3; ++dw) {
        int rr = r + dh - 1, cc = c + dw - 1;
        bool ok = iv && rr >= 0 && rr < 32 && cc >= 0 && cc < 32;
        #pragma unroll
        for (int ci = 0; ci < 3; ++ci)
          v[dh * 3 + dw][ci] = ok ? ip[ci * 1024 + rr * 32 + cc] : 0u;
      }
    }
    #pragma unroll
    for (int j = 0; j < 4; ++j) {
      short8 vh, vl;
      #pragma unroll
      for (int e = 0; e < 8; ++e) {
        int k = j * 8 + e;
        unsigned u = (k < 27) ? v[k / 3][k - 3 * (k / 3)] : 0u;
        vh[e] = (short)(u & 0xFFFFu);
        vl[e] = (short)(u >> 16);
      }
      *(short8*)&sIn[m * 72 + j * 8] = vh;
      *(short8*)&sIn[m * 72 + 32 + j * 8] = vl;
    }
  }
  __syncthreads();
  const int kb = (lane >> 4) * 8;
  const unsigned short* wb = wt + (size_t)cot * 4096 + (size_t)lane * 8;
  short8 Af[8];
  #pragma unroll
  for (int f = 0; f < 8; ++f)
    Af[f] = *(const short8*)(wb + (f >> 1) * 1024 + (f & 1) * 512);
  floatx4 acc[4][4];
  floatx4 zero = {0.f, 0.f, 0.f, 0.f};
  #pragma unroll
  for (int cg = 0; cg < 4; ++cg)
    #pragma unroll
    for (int g = 0; g < 4; ++g) acc[cg][g] = zero;
  short8 bh[4], bl[4];
  #pragma unroll
  for (int g = 0; g < 4; ++g) {
    int m = wv * 64 + g * 16 + (lane & 15);
    bh[g] = *(const short8*)&sIn[m * 72 + kb];
    bl[g] = *(const short8*)&sIn[m * 72 + 32 + kb];
  }
  #pragma unroll
  for (int cg = 0; cg < 4; ++cg) {
    #pragma unroll
    for (int g = 0; g < 4; ++g) {
      acc[cg][g] = __builtin_amdgcn_mfma_f32_16x16x32_bf16(Af[cg * 2 + 0], bh[g], acc[cg][g], 0, 0, 0);
      acc[cg][g] = __builtin_amdgcn_mfma_f32_16x16x32_bf16(Af[cg * 2 + 0], bl[g], acc[cg][g], 0, 0, 0);
      acc[cg][g] = __builtin_amdgcn_mfma_f32_16x16x32_bf16(Af[cg * 2 + 1], bh[g], acc[cg][g], 0, 0, 0);
    }
  }
  if (img >= nImgValid) return;
  #pragma unroll
  for (int g = 0; g < 4; ++g) {
    int mbase = wv * 64 + g * 16 + (lane & 15);
    int px = (r0 + (mbase >> 5)) * 32 + (mbase & 31);
    #pragma unroll
    for (int cg = 0; cg < 4; ++cg) {
      #pragma unroll
      for (int i2 = 0; i2 < 4; ++i2) {
        int co = cot * 64 + cg * 16 + (lane >> 4) * 4 + i2;
        out[((size_t)img * 128 + co) * 1024 + px] = acc[cg][g][i2] + bs[co];
      }
    }
  }
}

// ---------------------------------------------------------------------------
__global__ __launch_bounds__(256) void k_pool_u8(const uint8_t* __restrict__ in,
                                                 float* __restrict__ out,
                                                 int H, int total) {
  int idx = blockIdx.x * 256 + threadIdx.x;
  if (idx >= total) return;
  int Wo = H >> 1;
  int wo = idx % Wo;
  int t1 = idx / Wo;
  int ho = t1 % Wo;
  int bc = t1 / Wo;
  size_t base = ((size_t)bc * H + 2 * ho) * H + 2 * wo;
  out[idx] = 0.25f * ((float)in[base] + (float)in[base + 1] +
                      (float)in[base + H] + (float)in[base + H + 1]);
}

__global__ __launch_bounds__(256) void k_pool_f32(const float* __restrict__ in,
                                                  float* __restrict__ out,
                                                  int H, int total) {
  int idx = blockIdx.x * 256 + threadIdx.x;
  if (idx >= total) return;
  int Wo = H >> 1;
  int wo = idx % Wo;
  int t1 = idx / Wo;
  int ho = t1 % Wo;
  int bc = t1 / Wo;
  size_t base = ((size_t)bc * H + 2 * ho) * H + 2 * wo;
  out[idx] = 0.25f * (in[base] + in[base + 1] + in[base + H] + in[base + H + 1]);
}

// Integrate-and-fire; blockIdx.y = 64-t group. Optional second partial Xb.
__global__ __launch_bounds__(256) void k_if(const float* __restrict__ X,
                                            const float* __restrict__ Xb,
                                            uint8_t* __restrict__ Sp,
                                            const float* __restrict__ th,
                                            float* __restrict__ ssum,
                                            int C, int HW) {
  const int CHW = C * HW;
  int idx = blockIdx.x * 256 + threadIdx.x;
  if (idx >= CHW) return;
  int c = idx / HW;
  const float thv = th[c];
  size_t base = (size_t)blockIdx.y * 64 * CHW + idx;
  const float* p = X + base;
  const float* pb = Xb ? (Xb + base) : nullptr;
  uint8_t* q = Sp + base;
  float v = 0.f, ss = 0.f;
  #pragma unroll
  for (int t = 0; t < 64; ++t) {
    float xv = p[(size_t)t * CHW];
    if (pb) xv += pb[(size_t)t * CHW];
    v += xv;
    float s = (v >= thv) ? 1.f : 0.f;
    v -= s * thv;
    q[(size_t)t * CHW] = (uint8_t)s;
    ss += s;
  }
  if ((HW & 63) == 0) {
    for (int off = 32; off >= 1; off >>= 1) ss += __shfl_down(ss, off);
    if ((threadIdx.x & 63) == 0) atomicAdd(&ssum[c], ss);
  } else {
    atomicAdd(&ssum[c], ss);
  }
}

__global__ __launch_bounds__(256) void k_tty(const float* __restrict__ y4,
                                             float* __restrict__ yout,
                                             float* __restrict__ ysum,
                                             int C, int HW) {
  int idx = blockIdx.x * 256 + threadIdx.x;
  if (idx >= 4 * C * HW) return;
  int rem = idx % (C * HW);
  int c = rem / HW;
  float v = floorf(y4[idx] * 64.f) * 0.015625f;
  v = fminf(fmaxf(v, 0.f), 1.f);
  yout[idx] = v;
  if ((HW & 63) == 0) {
    for (int off = 32; off >= 1; off >>= 1) v += __shfl_down(v, off);
    if ((threadIdx.x & 63) == 0) atomicAdd(&ysum[c], v);
  } else {
    atomicAdd(&ysum[c], v);
  }
}

__global__ void k_thr(const float* __restrict__ thin,
                      const float* __restrict__ ssum,
                      const float* __restrict__ ysum,
                      float* __restrict__ dst, int C, float invmul) {
  int c = blockIdx.x * 256 + threadIdx.x;
  if (c >= C) return;
  float diff = (ysum[c] * 64.f - ssum[c]) * invmul;
  dst[c] = thin[c] - 0.1f * diff;
}

__global__ void k_sumspk(const uint8_t* __restrict__ A, float* __restrict__ S) {
  int idx = blockIdx.x * 256 + threadIdx.x;
  if (idx >= 4096) return;
  int n = idx >> 10, c = idx & 1023;
  const uint8_t* p = A + (size_t)n * 64 * 1024 + c;
  float s = 0.f;
  #pragma unroll
  for (int t = 0; t < 64; ++t) s += (float)p[t * 1024];
  S[idx] = s;
}

__global__ void k_cls(const float* __restrict__ S, const float* __restrict__ wc,
                      const float* __restrict__ bcp, float* __restrict__ out) {
  int idx = blockIdx.x * 256 + threadIdx.x;
  if (idx >= 400) return;
  int n = idx / 100, o = idx - (idx / 100) * 100;
  const float* sp = S + n * 1024;
  const float* wp = wc + o * 1024;
  float acc = 0.f;
  for (int c = 0; c < 1024; ++c) acc += wp[c] * sp[c];
  out[idx] = acc * 0.015625f + bcp[o];
}

extern "C" void kernel_launch(void* const* d_in, const int* in_sizes, int n_in,
                              void* d_out_v, int out_size, void* d_ws, size_t ws_size,
                              hipStream_t stream) {
  const float *Ws[7], *Bs[7], *Wa[7], *Ba[7];
  for (int i = 0; i < 7; ++i) {
    Ws[i] = (const float*)d_in[i * 4 + 0];
    Bs[i] = (const float*)d_in[i * 4 + 1];
    Wa[i] = (const float*)d_in[i * 4 + 2];
    Ba[i] = (const float*)d_in[i * 4 + 3];
  }
  const float* wc = (const float*)d_in[28];
  const float* bc = (const float*)d_in[29];
  const float* x  = (const float*)d_in[30];
  const float* TH[7];
  for (int i = 0; i < 7; ++i) TH[i] = (const float*)d_in[31 + i];
  const float* P[4];
  for (int i = 0; i < 4; ++i) P[i] = (const float*)d_in[38 + i];
  float* out = (float*)d_out_v;

  // ---- workspace (107.7 MB) ----
  float* w = (float*)d_ws;
  const size_t RF = 8536064;      // [WT | CF0] region, per-layer split
  float* Rb = w;
  size_t off = RF;
  float* xbar = w + off; off += 12288;    // packed u32 hi/lo
  float* yA   = w + off; off += 524288;
  float* yB   = w + off; off += 524288;
  float* y4   = w + off; off += 524288;
  float* S    = w + off; off += 4096;
  float* sums = w + off; off += 11 * 2048;
  uint8_t* SA = (uint8_t*)(w + off);
  uint8_t* SB = SA + 33554432;
  size_t total_bytes = off * sizeof(float) + (size_t)2 * 33554432;
  if (ws_size < total_bytes) return;
  unsigned short* WT = (unsigned short*)Rb;
  unsigned* XT2 = (unsigned*)SB;          // aliases SB (dead until L2 output)
  unsigned* xbar2 = (unsigned*)xbar;

  hipMemsetAsync(sums, 0, 11 * 2048 * sizeof(float), stream);
  k_tpack<<<3072, 256, 0, stream>>>(x, XT2);
  k_xbar_pack<<<48, 256, 0, stream>>>(x, xbar2);

  int stage = 0;

  // ---- L1 (MFMA im2col) ----
  {
    float* CF = Rb + 4096;                 // WT1 = 16 KB
    float* ss = sums; float* ys = ss + 1024;
    k_wxform1<<<2, 256, 0, stream>>>(Ws[0], WT);
    for (int c = 0; c < 4; ++c) {
      k_l1<<<dim3(2, 256), 256, 0, stream>>>(XT2 + (size_t)c * 64 * 3072, WT, Bs[0], CF, 64);
      k_if<<<dim3(512, 1), 256, 0, stream>>>(CF, nullptr, SA + (size_t)c * 64 * 131072,
                                             TH[0], ss, 128, 1024);
    }
    k_wxform1<<<2, 256, 0, stream>>>(Wa[0], WT);
    k_l1<<<dim3(2, 16), 256, 0, stream>>>(xbar2, WT, Ba[0], y4, 4);
    k_tty<<<2048, 256, 0, stream>>>(y4, yA, ys, 128, 1024);
    k_thr<<<1, 256, 0, stream>>>(TH[0], ss, ys, out + 400, 128, 1.0f / (4.f * 1024.f * 64.f));
    ++stage;
  }

  // ---- generic pad=1 MFMA layer, optional K-split x2 (CF1 = partial) ----
  auto mfma_layer = [&](const uint8_t* inS, uint8_t* outS, const float* inY, float* outY,
                        int li, int Ci, int Co, int W, int TRI, int tpi, int NIMG,
                        int chunkImgs, int kzn, float* CF1,
                        const float* thin, int outoff) {
    const int HW = W * W;
    const int CHWo = Co * HW;
    const int nch = Ci >> 5;
    float* ss = sums + stage * 2048; float* ys = ss + 1024;
    float* CF = Rb + (size_t)Co * Ci * 9;
    size_t osplit = (kzn == 2) ? (size_t)(CF1 - CF) : 0;
    int xgrid = ((Co / 64) * nch * 9 * 4 * 64 + 255) / 256;
    k_wxform<<<xgrid, 256, 0, stream>>>(Ws[li], WT, Ci, Co);
    int nchk = 256 / chunkImgs;
    int mt = (chunkImgs / NIMG) * tpi;
    for (int c = 0; c < nchk; ++c) {
      k_cmfma<uint8_t, false, 4><<<dim3(Co / 64, mt, kzn), 256, 0, stream>>>(
          inS + (size_t)c * chunkImgs * Ci * HW, WT, Bs[li], CF,
          Ci, Co, W, TRI, tpi, NIMG, chunkImgs, nch / kzn, osplit);
      k_if<<<dim3((CHWo + 255) / 256, chunkImgs / 64), 256, 0, stream>>>(
          CF, (kzn == 2) ? CF1 : nullptr,
          outS + (size_t)c * chunkImgs * CHWo, thin, ss, Co, HW);
    }
    k_wxform<<<xgrid, 256, 0, stream>>>(Wa[li], WT, Ci, Co);
    int mta = ((4 + NIMG - 1) / NIMG) * tpi;
    k_cmfma<float, false, 4><<<dim3(Co / 64, mta, 1), 256, 0, stream>>>(
        inY, WT, Ba[li], y4, Ci, Co, W, TRI, tpi, NIMG, 4, nch, 0);
    k_tty<<<(4 * CHWo + 255) / 256, 256, 0, stream>>>(y4, outY, ys, Co, HW);
    k_thr<<<(Co + 255) / 256, 256, 0, stream>>>(thin, ss, ys, out + outoff, Co,
                                                1.0f / (4.f * HW * 64.f));
    ++stage;
  };

  auto pool_stage = [&](const uint8_t* inS, uint8_t* outS, const float* inY, float* outY,
                        int C, int H, const float* pthr, int outoff) {
    const int Ho = H / 2, HWo = Ho * Ho;
    const int CHWo = C * HWo;
    float* CF = Rb;
    float* ss = sums + stage * 2048; float* ys = ss + 1024;
    int tot5 = 256 * CHWo;
    k_pool_u8<<<(tot5 + 255) / 256, 256, 0, stream>>>(inS, CF, H, tot5);
    k_if<<<dim3((CHWo + 255) / 256, 4), 256, 0, stream>>>(CF, nullptr, outS, pthr, ss, C, HWo);
    int tot4 = 4 * CHWo;
    k_pool_f32<<<(tot4 + 255) / 256, 256, 0, stream>>>(inY, y4, H, tot4);
    k_tty<<<(tot4 + 255) / 256, 256, 0, stream>>>(y4, outY, ys, C, HWo);
    k_thr<<<(C + 255) / 256, 256, 0, stream>>>(pthr, ss, ys, out + outoff, C,
                                               1.0f / (4.f * HWo * 64.f));
    ++stage;
  };

  // L2 (512 blocks already; no split)
  mfma_layer(SA, SB, yA, yB, 1, 128, 128, 32, 8, 4, 1, 64, 1, nullptr, TH[1], 528);
  // P1
  pool_stage(SB, SA, yB, yA, 128, 32, P[0], 3216);
  // L3: split x2, partial in SB tail (out spikes use SB[0,16.8M))
  mfma_layer(SA, SB, yA, yB, 2, 128, 256, 16, 16, 1, 1, 64, 2,
             (float*)(SB + 16777216), TH[2], 656);
  // L4: split x2, partial in SA tail
  mfma_layer(SB, SA, yB, yA, 3, 256, 256, 16, 16, 1, 1, 64, 2,
             (float*)(SA + 16777216), TH[3], 912);
  // P2
  pool_stage(SA, SB, yA, yB, 256, 16, P[1], 3344);
  // L5: split x2, partial in SA tail (spikes 8.4M)
  mfma_layer(SB, SA, yB, yA, 4, 256, 512, 8, 8, 1, 4, 128, 2,
             (float*)(SA + 8388608), TH[4], 1168);
  // L6: split x2, partial in SB tail
  mfma_layer(SA, SB, yA, yB, 5, 512, 512, 8, 8, 1, 4, 128, 2,
             (float*)(SB + 8388608), TH[5], 1680);
  // P3
  pool_stage(SB, SA, yB, yA, 512, 8, P[2], 3600);
  // L7 (pad=0), K-split 2 with partial buffers inside RF
  {
    float* ss = sums + stage * 2048; float* ys = ss + 1024;
    float* CF = Rb + (size_t)1024 * 512 * 9;    // 4.72M floats
    const size_t osplit = 1048576;              // 256*1024*4
    int xgrid = (16 * 16 * 9 * 4 * 64 + 255) / 256;
    k_wxform<<<xgrid, 256, 0, stream>>>(Ws[6], WT, 512, 1024);
    k_cmfma<uint8_t, true, 2><<<dim3(16, 8, 2), 256, 0, stream>>>(
        SA, WT, Bs[6], CF, 512, 1024, 4, 0, 1, 0, 256, 8, osplit);
    k_if<<<dim3(16, 4), 256, 0, stream>>>(CF, CF + osplit, SB, TH[6], ss, 1024, 4);
    k_wxform<<<xgrid, 256, 0, stream>>>(Wa[6], WT, 512, 1024);
    k_cmfma<float, true, 2><<<dim3(16, 1, 1), 256, 0, stream>>>(
        yA, WT, Ba[6], y4, 512, 1024, 4, 0, 1, 0, 4, 16, 0);
    k_tty<<<64, 256, 0, stream>>>(y4, yB, ys, 1024, 4);
    k_thr<<<4, 256, 0, stream>>>(TH[6], ss, ys, out + 2192, 1024, 1.0f / 1024.f);
    ++stage;
  }
  // P4
  pool_stage(SB, SA, yB, yA, 1024, 2, P[3], 4112);
  // classifier
  k_sumspk<<<16, 256, 0, stream>>>(SA, S);
  k_cls<<<2, 256, 0, stream>>>(S, wc, bc, out);
}

// Round 9
// 2118.856 us; speedup vs baseline: 5.8610x; 1.2568x over previous
//
#include <hip/hip_runtime.h>
#include <cstdint>
#include <cstddef>

// ---------------------------------------------------------------------------
// SNN "CatNet" forward, MFMA v4.
// Spiking tensors: uint8 [(n*64+t), C, H, W] (exact 0/1).
// All convs run as bf16 MFMA implicit-GEMM with hi/lo split weights.
// v4: analog-path (batch-4) convs re-gridded: G=1 wave-tile + deep K-split
// (partials in y4, summed by k_tty) -> >=128 blocks/dispatch.
// ---------------------------------------------------------------------------

typedef short short8 __attribute__((ext_vector_type(8)));   // 8 bf16
typedef float floatx4 __attribute__((ext_vector_type(4)));

__device__ __forceinline__ unsigned short f2bf_rne(float f) {
  unsigned u = __float_as_uint(f);
  return (unsigned short)((u + 0x7FFFu + ((u >> 16) & 1u)) >> 16);
}
__device__ __forceinline__ float bf2f(unsigned short h) {
  return __uint_as_float((unsigned)h << 16);
}

// ---------------------------------------------------------------------------
// Weight pre-transform (3x3 layers): W f32 [Co][Ci][3][3] -> bf16 hi/lo frags.
// frag(cot,ch,tap,cg,h) at shorts: (cot*nch+ch)*36864 + tap*4096 + cg*1024
//                                  + h*512 + lane*8
// ---------------------------------------------------------------------------
__global__ __launch_bounds__(256) void k_wxform(const float* __restrict__ Wsrc,
                                                unsigned short* __restrict__ wt,
                                                int Ci, int Co) {
  const int nch = Ci >> 5;
  const int total = (Co >> 6) * nch * 9 * 4 * 64;
  int idx = blockIdx.x * 256 + threadIdx.x;
  if (idx >= total) return;
  int lane = idx & 63;
  int t2 = idx >> 6;
  int cg = t2 & 3;
  int t3 = t2 >> 2;
  int tap = t3 % 9;
  int t4 = t3 / 9;
  int ch = t4 % nch;
  int cot = t4 / nch;
  int co = cot * 64 + cg * 16 + (lane & 15);
  int cib = ch * 32 + (lane >> 4) * 8;
  short8 vh, vl;
  #pragma unroll
  for (int j = 0; j < 8; ++j) {
    float wv = Wsrc[((size_t)co * Ci + cib + j) * 9 + tap];
    unsigned short h = f2bf_rne(wv);
    vh[j] = (short)h;
    vl[j] = (short)f2bf_rne(wv - bf2f(h));
  }
  size_t base = ((((size_t)cot * nch + ch) * 9 + tap) * 4 + cg) * 1024 + (size_t)lane * 8;
  *(short8*)&wt[base] = vh;
  *(short8*)&wt[base + 512] = vl;
}

// L1 weight transform: W f32 [128][3][3][3] -> K=32 frags, k = tap*3+ci.
__global__ __launch_bounds__(256) void k_wxform1(const float* __restrict__ Wsrc,
                                                 unsigned short* __restrict__ wt) {
  int idx = blockIdx.x * 256 + threadIdx.x;   // 512 total
  if (idx >= 512) return;
  int lane = idx & 63, cg = (idx >> 6) & 3, cot = idx >> 8;
  int co = cot * 64 + cg * 16 + (lane & 15);
  short8 vh, vl;
  #pragma unroll
  for (int e = 0; e < 8; ++e) {
    int k = (lane >> 4) * 8 + e;
    float wv = 0.f;
    if (k < 27) { int tap = k / 3, ci = k - 3 * tap; wv = Wsrc[(co * 3 + ci) * 9 + tap]; }
    unsigned short h = f2bf_rne(wv);
    vh[e] = (short)h;
    vl[e] = (short)f2bf_rne(wv - bf2f(h));
  }
  size_t base = (size_t)cot * 4096 + cg * 1024 + (size_t)lane * 8;
  *(short8*)&wt[base] = vh;
  *(short8*)&wt[base + 512] = vl;
}

// Transpose+pack x: [n][c][hw][t] f32 -> XT2[(n*64+t)][c][hw] u32 = hi|lo<<16
__global__ __launch_bounds__(256) void k_tpack(const float* __restrict__ x,
                                               unsigned* __restrict__ XT2) {
  int idx = blockIdx.x * 256 + threadIdx.x;   // 786432
  int b = idx / 3072;
  int rem = idx - b * 3072;
  int t = b & 63, n = b >> 6;
  float f = x[((size_t)(n * 3072 + rem)) * 64 + t];
  unsigned short h = f2bf_rne(f);
  unsigned short l = f2bf_rne(f - bf2f(h));
  XT2[idx] = (unsigned)h | ((unsigned)l << 16);
}

__global__ __launch_bounds__(256) void k_xbar_pack(const float* __restrict__ x,
                                                   unsigned* __restrict__ xb) {
  int idx = blockIdx.x * 256 + threadIdx.x;   // 12288
  if (idx >= 12288) return;
  const float* p = x + (size_t)idx * 64;
  float s = 0.f;
  #pragma unroll
  for (int t = 0; t < 64; ++t) s += p[t];
  s *= 0.015625f;
  unsigned short h = f2bf_rne(s);
  unsigned short l = f2bf_rne(s - bf2f(h));
  xb[idx] = (unsigned)h | ((unsigned)l << 16);
}

// ---------------------------------------------------------------------------
// MFMA conv, generic 3x3. PAD0=false: pad=1 square W; PAD0=true: L7 (4x4->2x2).
// Block: 256 thr / 4 waves; wave-tile 64co x (G*16)px. A from global (per-tap
// double buffer), B from LDS (stride-40-short rows, conflict-free b128).
// grid.z = K-split: chunks [z*nchPer, (z+1)*nchPer), out += z*osplit,
// bias added only by z==0.
// ---------------------------------------------------------------------------
template <typename T, bool PAD0, int G>
__global__ __launch_bounds__(256, 1) void k_cmfma(
    const T* __restrict__ in, const unsigned short* __restrict__ wt,
    const float* __restrict__ bs, float* __restrict__ out,
    int Ci, int Co, int W, int TRI, int tpi, int NIMG, int nImgValid,
    int nchPer, size_t osplit) {
  constexpr int MT = 4 * G * 16;             // block m-tile
  constexpr int PPXMAX = PAD0 ? (MT / 4) * 16 : 400;
  __shared__ unsigned short sIn[PPXMAX * 40];
  const int tid = threadIdx.x;
  const int lane = tid & 63;
  const int wv = tid >> 6;
  const int cot = blockIdx.x;
  const int mtile = blockIdx.y;
  const int kz = blockIdx.z;
  const int nch = Ci >> 5;
  const int nchA = kz * nchPer, nchB = nchA + nchPer;
  out += (size_t)kz * osplit;
  const int addBias = (kz == 0);

  int img_first, r0 = 0, PPR, PPX;
  if constexpr (PAD0) {
    img_first = mtile * (MT / 4);
    PPR = 16; PPX = (MT / 4) * 16;
  } else {
    img_first = (mtile / tpi) * NIMG;
    r0 = (mtile % tpi) * TRI;
    PPR = (TRI + 2) * (W + 2);
    PPX = NIMG * PPR;
  }
  const int TRW = TRI * W;

  // output / B-fragment mapping
  int p0[G], mimg[G], mopx[G];
  #pragma unroll
  for (int g = 0; g < G; ++g) {
    int m = wv * (G * 16) + g * 16 + (lane & 15);
    int limg;
    if constexpr (PAD0) {
      limg = m >> 2;
      int o = m & 3;
      p0[g] = limg * 16 + (o >> 1) * 4 + (o & 1);
      mopx[g] = (o >> 1) * 2 + (o & 1);
    } else {
      limg = m / TRW;
      int rm = m - limg * TRW;
      int r = rm / W, c = rm - r * W;
      p0[g] = limg * PPR + r * (W + 2) + c;
      mopx[g] = (r0 + r) * W + c;
    }
    mimg[g] = img_first + limg;
  }
  int psh[9];
  #pragma unroll
  for (int t = 0; t < 9; ++t) {
    int dh = t / 3, dw = t - dh * 3;
    psh[t] = PAD0 ? (dh * 4 + dw) : (dh * (W + 2) + dw);
  }

  // staging precompute (<=2 px per thread), idiv only here
  const int HWin = PAD0 ? 16 : W * W;
  int sgofs[2]; bool svalid[2];
  #pragma unroll
  for (int i = 0; i < 2; ++i) {
    int p = tid + i * 256;
    svalid[i] = false; sgofs[i] = 0;
    if (p < PPX) {
      int limg, gpx;
      if constexpr (PAD0) {
        limg = p >> 4; gpx = p & 15;
      } else {
        limg = p / PPR;
        int rem = p - limg * PPR;
        int pr = rem / (W + 2), pc = rem - pr * (W + 2);
        int gr = r0 + pr - 1, gc = pc - 1;
        gpx = (gr >= 0 && gr < W && gc >= 0 && gc < W) ? gr * W + gc : -1;
      }
      int img = img_first + limg;
      if (gpx >= 0 && img < nImgValid) {
        svalid[i] = true;
        sgofs[i] = img * Ci * HWin + gpx;
      }
    }
  }
  const int kb = (lane >> 4) * 8;

  floatx4 acc[4][G];
  floatx4 zero = {0.f, 0.f, 0.f, 0.f};
  #pragma unroll
  for (int cg = 0; cg < 4; ++cg)
    #pragma unroll
    for (int g = 0; g < G; ++g) acc[cg][g] = zero;

  for (int ch = nchA; ch < nchB; ++ch) {
    const int ci0 = ch * 32;
    // ---- gather all staging bytes into regs (one wait), then write LDS ----
    unsigned rawu[2][32];
    float rawf[2][32];
    #pragma unroll
    for (int i = 0; i < 2; ++i) {
      if (tid + i * 256 < PPX && svalid[i]) {
        const T* sp = in + sgofs[i] + (size_t)ci0 * HWin;
        #pragma unroll
        for (int k = 0; k < 32; ++k) {
          if constexpr (sizeof(T) == 1) rawu[i][k] = sp[(size_t)k * HWin];
          else rawf[i][k] = ((const float*)sp)[(size_t)k * HWin];
        }
      }
    }
    #pragma unroll
    for (int i = 0; i < 2; ++i) {
      int p = tid + i * 256;
      if (p < PPX) {
        unsigned short* dst = &sIn[p * 40];
        if (svalid[i]) {
          #pragma unroll
          for (int j = 0; j < 4; ++j) {
            short8 v;
            #pragma unroll
            for (int e = 0; e < 8; ++e) {
              if constexpr (sizeof(T) == 1)
                v[e] = rawu[i][j * 8 + e] ? (short)0x3F80 : (short)0;
              else
                v[e] = (short)f2bf_rne(rawf[i][j * 8 + e]);
            }
            *(short8*)&dst[j * 8] = v;
          }
        } else {
          short8 z = {};
          #pragma unroll
          for (int j = 0; j < 4; ++j) *(short8*)&dst[j * 8] = z;
        }
      }
    }
    __syncthreads();
    // ---- taps: A from global (double-buffered), B from LDS ----
    const unsigned short* wb = wt + ((size_t)(cot * nch + ch)) * 36864 + (size_t)lane * 8;
    short8 A[2][8];
    #pragma unroll
    for (int f = 0; f < 8; ++f)
      A[0][f] = *(const short8*)(wb + (f >> 1) * 1024 + (f & 1) * 512);
    #pragma unroll
    for (int t = 0; t < 9; ++t) {
      const int cur = t & 1;
      if (t < 8) {
        #pragma unroll
        for (int f = 0; f < 8; ++f)
          A[cur ^ 1][f] = *(const short8*)(wb + (size_t)(t + 1) * 4096 + (f >> 1) * 1024 + (f & 1) * 512);
      }
      short8 b[G];
      #pragma unroll
      for (int g = 0; g < G; ++g)
        b[g] = *(const short8*)&sIn[(p0[g] + psh[t]) * 40 + kb];
      #pragma unroll
      for (int cg = 0; cg < 4; ++cg) {
        #pragma unroll
        for (int g = 0; g < G; ++g) {
          acc[cg][g] = __builtin_amdgcn_mfma_f32_16x16x32_bf16(A[cur][cg * 2 + 0], b[g], acc[cg][g], 0, 0, 0);
          acc[cg][g] = __builtin_amdgcn_mfma_f32_16x16x32_bf16(A[cur][cg * 2 + 1], b[g], acc[cg][g], 0, 0, 0);
        }
      }
    }
    __syncthreads();
  }
  // ---- epilogue: row=(lane>>4)*4+i -> co, col=lane&15 -> px ----
  const int HWout = PAD0 ? 4 : W * W;
  #pragma unroll
  for (int g = 0; g < G; ++g) {
    if (mimg[g] >= nImgValid) continue;
    #pragma unroll
    for (int cg = 0; cg < 4; ++cg) {
      #pragma unroll
      for (int i2 = 0; i2 < 4; ++i2) {
        int co = cot * 64 + cg * 16 + (lane >> 4) * 4 + i2;
        float bv = addBias ? bs[co] : 0.f;
        out[((size_t)mimg[g] * Co + co) * HWout + mopx[g]] = acc[cg][g][i2] + bv;
      }
    }
  }
}

// ---------------------------------------------------------------------------
// L1 MFMA conv: K=32 im2col (k=tap*3+ci), input packed hi/lo u32.
// ---------------------------------------------------------------------------
__global__ __launch_bounds__(256, 1) void k_l1(const unsigned* __restrict__ xin,
                                               const unsigned short* __restrict__ wt,
                                               const float* __restrict__ bs,
                                               float* __restrict__ out,
                                               int nImgValid) {
  __shared__ unsigned short sIn[256 * 72];   // [m][hi(32) | lo(32)], stride 72
  const int tid = threadIdx.x, lane = tid & 63, wv = tid >> 6;
  const int cot = blockIdx.x, mtile = blockIdx.y;
  const int img = mtile >> 2;
  const int r0 = (mtile & 3) * 8;
  {
    int m = tid;
    int r = r0 + (m >> 5), c = m & 31;
    const unsigned* ip = xin + (size_t)img * 3072;
    unsigned v[9][3];
    bool iv = (img < nImgValid);
    #pragma unroll
    for (int dh = 0; dh < 3; ++dh) {
      #pragma unroll
      for (int dw = 0; dw < 3; ++dw) {
        int rr = r + dh - 1, cc = c + dw - 1;
        bool ok = iv && rr >= 0 && rr < 32 && cc >= 0 && cc < 32;
        #pragma unroll
        for (int ci = 0; ci < 3; ++ci)
          v[dh * 3 + dw][ci] = ok ? ip[ci * 1024 + rr * 32 + cc] : 0u;
      }
    }
    #pragma unroll
    for (int j = 0; j < 4; ++j) {
      short8 vh, vl;
      #pragma unroll
      for (int e = 0; e < 8; ++e) {
        int k = j * 8 + e;
        unsigned u = (k < 27) ? v[k / 3][k - 3 * (k / 3)] : 0u;
        vh[e] = (short)(u & 0xFFFFu);
        vl[e] = (short)(u >> 16);
      }
      *(short8*)&sIn[m * 72 + j * 8] = vh;
      *(short8*)&sIn[m * 72 + 32 + j * 8] = vl;
    }
  }
  __syncthreads();
  const int kb = (lane >> 4) * 8;
  const unsigned short* wb = wt + (size_t)cot * 4096 + (size_t)lane * 8;
  short8 Af[8];
  #pragma unroll
  for (int f = 0; f < 8; ++f)
    Af[f] = *(const short8*)(wb + (f >> 1) * 1024 + (f & 1) * 512);
  floatx4 acc[4][4];
  floatx4 zero = {0.f, 0.f, 0.f, 0.f};
  #pragma unroll
  for (int cg = 0; cg < 4; ++cg)
    #pragma unroll
    for (int g = 0; g < 4; ++g) acc[cg][g] = zero;
  short8 bh[4], bl[4];
  #pragma unroll
  for (int g = 0; g < 4; ++g) {
    int m = wv * 64 + g * 16 + (lane & 15);
    bh[g] = *(const short8*)&sIn[m * 72 + kb];
    bl[g] = *(const short8*)&sIn[m * 72 + 32 + kb];
  }
  #pragma unroll
  for (int cg = 0; cg < 4; ++cg) {
    #pragma unroll
    for (int g = 0; g < 4; ++g) {
      acc[cg][g] = __builtin_amdgcn_mfma_f32_16x16x32_bf16(Af[cg * 2 + 0], bh[g], acc[cg][g], 0, 0, 0);
      acc[cg][g] = __builtin_amdgcn_mfma_f32_16x16x32_bf16(Af[cg * 2 + 0], bl[g], acc[cg][g], 0, 0, 0);
      acc[cg][g] = __builtin_amdgcn_mfma_f32_16x16x32_bf16(Af[cg * 2 + 1], bh[g], acc[cg][g], 0, 0, 0);
    }
  }
  if (img >= nImgValid) return;
  #pragma unroll
  for (int g = 0; g < 4; ++g) {
    int mbase = wv * 64 + g * 16 + (lane & 15);
    int px = (r0 + (mbase >> 5)) * 32 + (mbase & 31);
    #pragma unroll
    for (int cg = 0; cg < 4; ++cg) {
      #pragma unroll
      for (int i2 = 0; i2 < 4; ++i2) {
        int co = cot * 64 + cg * 16 + (lane >> 4) * 4 + i2;
        out[((size_t)img * 128 + co) * 1024 + px] = acc[cg][g][i2] + bs[co];
      }
    }
  }
}

// ---------------------------------------------------------------------------
__global__ __launch_bounds__(256) void k_pool_u8(const uint8_t* __restrict__ in,
                                                 float* __restrict__ out,
                                                 int H, int total) {
  int idx = blockIdx.x * 256 + threadIdx.x;
  if (idx >= total) return;
  int Wo = H >> 1;
  int wo = idx % Wo;
  int t1 = idx / Wo;
  int ho = t1 % Wo;
  int bc = t1 / Wo;
  size_t base = ((size_t)bc * H + 2 * ho) * H + 2 * wo;
  out[idx] = 0.25f * ((float)in[base] + (float)in[base + 1] +
                      (float)in[base + H] + (float)in[base + H + 1]);
}

__global__ __launch_bounds__(256) void k_pool_f32(const float* __restrict__ in,
                                                  float* __restrict__ out,
                                                  int H, int total) {
  int idx = blockIdx.x * 256 + threadIdx.x;
  if (idx >= total) return;
  int Wo = H >> 1;
  int wo = idx % Wo;
  int t1 = idx / Wo;
  int ho = t1 % Wo;
  int bc = t1 / Wo;
  size_t base = ((size_t)bc * H + 2 * ho) * H + 2 * wo;
  out[idx] = 0.25f * (in[base] + in[base + 1] + in[base + H] + in[base + H + 1]);
}

// Integrate-and-fire; blockIdx.y = 64-t group. Optional second partial Xb.
__global__ __launch_bounds__(256) void k_if(const float* __restrict__ X,
                                            const float* __restrict__ Xb,
                                            uint8_t* __restrict__ Sp,
                                            const float* __restrict__ th,
                                            float* __restrict__ ssum,
                                            int C, int HW) {
  const int CHW = C * HW;
  int idx = blockIdx.x * 256 + threadIdx.x;
  if (idx >= CHW) return;
  int c = idx / HW;
  const float thv = th[c];
  size_t base = (size_t)blockIdx.y * 64 * CHW + idx;
  const float* p = X + base;
  const float* pb = Xb ? (Xb + base) : nullptr;
  uint8_t* q = Sp + base;
  float v = 0.f, ss = 0.f;
  #pragma unroll
  for (int t = 0; t < 64; ++t) {
    float xv = p[(size_t)t * CHW];
    if (pb) xv += pb[(size_t)t * CHW];
    v += xv;
    float s = (v >= thv) ? 1.f : 0.f;
    v -= s * thv;
    q[(size_t)t * CHW] = (uint8_t)s;
    ss += s;
  }
  if ((HW & 63) == 0) {
    for (int off = 32; off >= 1; off >>= 1) ss += __shfl_down(ss, off);
    if ((threadIdx.x & 63) == 0) atomicAdd(&ssum[c], ss);
  } else {
    atomicAdd(&ssum[c], ss);
  }
}

// Analog quantize; sums nparts partial conv outputs (K-split) first.
__global__ __launch_bounds__(256) void k_tty(const float* __restrict__ y4,
                                             float* __restrict__ yout,
                                             float* __restrict__ ysum,
                                             int C, int HW,
                                             int nparts, int pstride) {
  int idx = blockIdx.x * 256 + threadIdx.x;
  if (idx >= 4 * C * HW) return;
  int rem = idx % (C * HW);
  int c = rem / HW;
  float xv = 0.f;
  for (int p = 0; p < nparts; ++p) xv += y4[idx + (size_t)p * pstride];
  float v = floorf(xv * 64.f) * 0.015625f;
  v = fminf(fmaxf(v, 0.f), 1.f);
  yout[idx] = v;
  if ((HW & 63) == 0) {
    for (int off = 32; off >= 1; off >>= 1) v += __shfl_down(v, off);
    if ((threadIdx.x & 63) == 0) atomicAdd(&ysum[c], v);
  } else {
    atomicAdd(&ysum[c], v);
  }
}

__global__ void k_thr(const float* __restrict__ thin,
                      const float* __restrict__ ssum,
                      const float* __restrict__ ysum,
                      float* __restrict__ dst, int C, float invmul) {
  int c = blockIdx.x * 256 + threadIdx.x;
  if (c >= C) return;
  float diff = (ysum[c] * 64.f - ssum[c]) * invmul;
  dst[c] = thin[c] - 0.1f * diff;
}

__global__ void k_sumspk(const uint8_t* __restrict__ A, float* __restrict__ S) {
  int idx = blockIdx.x * 256 + threadIdx.x;
  if (idx >= 4096) return;
  int n = idx >> 10, c = idx & 1023;
  const uint8_t* p = A + (size_t)n * 64 * 1024 + c;
  float s = 0.f;
  #pragma unroll
  for (int t = 0; t < 64; ++t) s += (float)p[t * 1024];
  S[idx] = s;
}

__global__ void k_cls(const float* __restrict__ S, const float* __restrict__ wc,
                      const float* __restrict__ bcp, float* __restrict__ out) {
  int idx = blockIdx.x * 256 + threadIdx.x;
  if (idx >= 400) return;
  int n = idx / 100, o = idx - (idx / 100) * 100;
  const float* sp = S + n * 1024;
  const float* wp = wc + o * 1024;
  float acc = 0.f;
  for (int c = 0; c < 1024; ++c) acc += wp[c] * sp[c];
  out[idx] = acc * 0.015625f + bcp[o];
}

extern "C" void kernel_launch(void* const* d_in, const int* in_sizes, int n_in,
                              void* d_out_v, int out_size, void* d_ws, size_t ws_size,
                              hipStream_t stream) {
  const float *Ws[7], *Bs[7], *Wa[7], *Ba[7];
  for (int i = 0; i < 7; ++i) {
    Ws[i] = (const float*)d_in[i * 4 + 0];
    Bs[i] = (const float*)d_in[i * 4 + 1];
    Wa[i] = (const float*)d_in[i * 4 + 2];
    Ba[i] = (const float*)d_in[i * 4 + 3];
  }
  const float* wc = (const float*)d_in[28];
  const float* bc = (const float*)d_in[29];
  const float* x  = (const float*)d_in[30];
  const float* TH[7];
  for (int i = 0; i < 7; ++i) TH[i] = (const float*)d_in[31 + i];
  const float* P[4];
  for (int i = 0; i < 4; ++i) P[i] = (const float*)d_in[38 + i];
  float* out = (float*)d_out_v;

  // ---- workspace (107.7 MB) ----
  float* w = (float*)d_ws;
  const size_t RF = 8536064;      // [WT | CF0] region, per-layer split
  float* Rb = w;
  size_t off = RF;
  float* xbar = w + off; off += 12288;    // packed u32 hi/lo
  float* yA   = w + off; off += 524288;
  float* yB   = w + off; off += 524288;
  float* y4   = w + off; off += 524288;
  float* S    = w + off; off += 4096;
  float* sums = w + off; off += 11 * 2048;
  uint8_t* SA = (uint8_t*)(w + off);
  uint8_t* SB = SA + 33554432;
  size_t total_bytes = off * sizeof(float) + (size_t)2 * 33554432;
  if (ws_size < total_bytes) return;
  unsigned short* WT = (unsigned short*)Rb;
  unsigned* XT2 = (unsigned*)SB;          // aliases SB (dead until L2 output)
  unsigned* xbar2 = (unsigned*)xbar;

  hipMemsetAsync(sums, 0, 11 * 2048 * sizeof(float), stream);
  k_tpack<<<3072, 256, 0, stream>>>(x, XT2);
  k_xbar_pack<<<48, 256, 0, stream>>>(x, xbar2);

  int stage = 0;

  // ---- L1 (MFMA im2col) ----
  {
    float* CF = Rb + 4096;                 // WT1 = 16 KB
    float* ss = sums; float* ys = ss + 1024;
    k_wxform1<<<2, 256, 0, stream>>>(Ws[0], WT);
    for (int c = 0; c < 4; ++c) {
      k_l1<<<dim3(2, 256), 256, 0, stream>>>(XT2 + (size_t)c * 64 * 3072, WT, Bs[0], CF, 64);
      k_if<<<dim3(512, 1), 256, 0, stream>>>(CF, nullptr, SA + (size_t)c * 64 * 131072,
                                             TH[0], ss, 128, 1024);
    }
    k_wxform1<<<2, 256, 0, stream>>>(Wa[0], WT);
    k_l1<<<dim3(2, 16), 256, 0, stream>>>(xbar2, WT, Ba[0], y4, 4);
    k_tty<<<2048, 256, 0, stream>>>(y4, yA, ys, 128, 1024, 1, 0);
    k_thr<<<1, 256, 0, stream>>>(TH[0], ss, ys, out + 400, 128, 1.0f / (4.f * 1024.f * 64.f));
    ++stage;
  }

  // ---- generic pad=1 MFMA layer ----
  // Spike conv: G=4 tile, optional kz=2 (partial CF1). Analog conv (batch 4):
  // G=1 tile, aTRI/atpi geometry, akz K-split with partials in y4.
  auto mfma_layer = [&](const uint8_t* inS, uint8_t* outS, const float* inY, float* outY,
                        int li, int Ci, int Co, int W, int TRI, int tpi, int NIMG,
                        int chunkImgs, int kzn, float* CF1,
                        int aTRI, int atpi, int akz,
                        const float* thin, int outoff) {
    const int HW = W * W;
    const int CHWo = Co * HW;
    const int nch = Ci >> 5;
    float* ss = sums + stage * 2048; float* ys = ss + 1024;
    float* CF = Rb + (size_t)Co * Ci * 9;
    size_t osplit = (kzn == 2) ? (size_t)(CF1 - CF) : 0;
    int xgrid = ((Co / 64) * nch * 9 * 4 * 64 + 255) / 256;
    k_wxform<<<xgrid, 256, 0, stream>>>(Ws[li], WT, Ci, Co);
    int nchk = 256 / chunkImgs;
    int mt = (chunkImgs / NIMG) * tpi;
    for (int c = 0; c < nchk; ++c) {
      k_cmfma<uint8_t, false, 4><<<dim3(Co / 64, mt, kzn), 256, 0, stream>>>(
          inS + (size_t)c * chunkImgs * Ci * HW, WT, Bs[li], CF,
          Ci, Co, W, TRI, tpi, NIMG, chunkImgs, nch / kzn, osplit);
      k_if<<<dim3((CHWo + 255) / 256, chunkImgs / 64), 256, 0, stream>>>(
          CF, (kzn == 2) ? CF1 : nullptr,
          outS + (size_t)c * chunkImgs * CHWo, thin, ss, Co, HW);
    }
    k_wxform<<<xgrid, 256, 0, stream>>>(Wa[li], WT, Ci, Co);
    int aosplit = 4 * CHWo;
    k_cmfma<float, false, 1><<<dim3(Co / 64, 4 * atpi, akz), 256, 0, stream>>>(
        inY, WT, Ba[li], y4, Ci, Co, W, aTRI, atpi, 1, 4, nch / akz, (size_t)aosplit);
    k_tty<<<(4 * CHWo + 255) / 256, 256, 0, stream>>>(y4, outY, ys, Co, HW, akz, aosplit);
    k_thr<<<(Co + 255) / 256, 256, 0, stream>>>(thin, ss, ys, out + outoff, Co,
                                                1.0f / (4.f * HW * 64.f));
    ++stage;
  };

  auto pool_stage = [&](const uint8_t* inS, uint8_t* outS, const float* inY, float* outY,
                        int C, int H, const float* pthr, int outoff) {
    const int Ho = H / 2, HWo = Ho * Ho;
    const int CHWo = C * HWo;
    float* CF = Rb;
    float* ss = sums + stage * 2048; float* ys = ss + 1024;
    int tot5 = 256 * CHWo;
    k_pool_u8<<<(tot5 + 255) / 256, 256, 0, stream>>>(inS, CF, H, tot5);
    k_if<<<dim3((CHWo + 255) / 256, 4), 256, 0, stream>>>(CF, nullptr, outS, pthr, ss, C, HWo);
    int tot4 = 4 * CHWo;
    k_pool_f32<<<(tot4 + 255) / 256, 256, 0, stream>>>(inY, y4, H, tot4);
    k_tty<<<(tot4 + 255) / 256, 256, 0, stream>>>(y4, outY, ys, C, HWo, 1, 0);
    k_thr<<<(C + 255) / 256, 256, 0, stream>>>(pthr, ss, ys, out + outoff, C,
                                               1.0f / (4.f * HWo * 64.f));
    ++stage;
  };

  // L2: spike no split; analog aTRI=2, atpi=16 (mta=64), akz=1
  mfma_layer(SA, SB, yA, yB, 1, 128, 128, 32, 8, 4, 1, 64, 1, nullptr,
             2, 16, 1, TH[1], 528);
  // P1
  pool_stage(SB, SA, yB, yA, 128, 32, P[0], 3216);
  // L3: spike kz=2 (partial in SB tail); analog aTRI=4, atpi=4, akz=2
  mfma_layer(SA, SB, yA, yB, 2, 128, 256, 16, 16, 1, 1, 64, 2,
             (float*)(SB + 16777216), 4, 4, 2, TH[2], 656);
  // L4
  mfma_layer(SB, SA, yB, yA, 3, 256, 256, 16, 16, 1, 1, 64, 2,
             (float*)(SA + 16777216), 4, 4, 2, TH[3], 912);
  // P2
  pool_stage(SA, SB, yA, yB, 256, 16, P[1], 3344);
  // L5: analog aTRI=8, atpi=1 (mta=4), akz=4
  mfma_layer(SB, SA, yB, yA, 4, 256, 512, 8, 8, 1, 4, 128, 2,
             (float*)(SA + 8388608), 8, 1, 4, TH[4], 1168);
  // L6: akz=4 (nch=16 -> nchPer=4)
  mfma_layer(SA, SB, yA, yB, 5, 512, 512, 8, 8, 1, 4, 128, 2,
             (float*)(SB + 8388608), 8, 1, 4, TH[5], 1680);
  // P3
  pool_stage(SB, SA, yB, yA, 512, 8, P[2], 3600);
  // L7 (pad=0): spike kz=2 in RF; analog G=1 PAD0, akz=8, partials in y4
  {
    float* ss = sums + stage * 2048; float* ys = ss + 1024;
    float* CF = Rb + (size_t)1024 * 512 * 9;    // 4.72M floats
    const size_t osplit = 1048576;              // 256*1024*4
    int xgrid = (16 * 16 * 9 * 4 * 64 + 255) / 256;
    k_wxform<<<xgrid, 256, 0, stream>>>(Ws[6], WT, 512, 1024);
    k_cmfma<uint8_t, true, 2><<<dim3(16, 8, 2), 256, 0, stream>>>(
        SA, WT, Bs[6], CF, 512, 1024, 4, 0, 1, 0, 256, 8, osplit);
    k_if<<<dim3(16, 4), 256, 0, stream>>>(CF, CF + osplit, SB, TH[6], ss, 1024, 4);
    k_wxform<<<xgrid, 256, 0, stream>>>(Wa[6], WT, 512, 1024);
    k_cmfma<float, true, 1><<<dim3(16, 1, 8), 256, 0, stream>>>(
        yA, WT, Ba[6], y4, 512, 1024, 4, 0, 1, 0, 4, 2, 16384);
    k_tty<<<64, 256, 0, stream>>>(y4, yB, ys, 1024, 4, 8, 16384);
    k_thr<<<4, 256, 0, stream>>>(TH[6], ss, ys, out + 2192, 1024, 1.0f / 1024.f);
    ++stage;
  }
  // P4
  pool_stage(SB, SA, yB, yA, 1024, 2, P[3], 4112);
  // classifier
  k_sumspk<<<16, 256, 0, stream>>>(SA, S);
  k_cls<<<2, 256, 0, stream>>>(S, wc, bc, out);
}

// Round 10
// 1973.624 us; speedup vs baseline: 6.2923x; 1.0736x over previous
//
#include <hip/hip_runtime.h>
#include <cstdint>
#include <cstddef>

// ---------------------------------------------------------------------------
// SNN "CatNet" forward, MFMA v5.
// Spiking tensors: uint8 [(n*64+t), C, H, W] (exact 0/1).
// All convs run as bf16 MFMA implicit-GEMM with hi/lo split weights.
// v5: spike convs G=2 wave-tile (grid >=1024 -> 4 blocks/CU), no explicit
// raw-gather (regs freed -> 3+ waves/SIMD), L7 spike K-split x4,
// generalized k_if partial summation.
// ---------------------------------------------------------------------------

typedef short short8 __attribute__((ext_vector_type(8)));   // 8 bf16
typedef float floatx4 __attribute__((ext_vector_type(4)));

__device__ __forceinline__ unsigned short f2bf_rne(float f) {
  unsigned u = __float_as_uint(f);
  return (unsigned short)((u + 0x7FFFu + ((u >> 16) & 1u)) >> 16);
}
__device__ __forceinline__ float bf2f(unsigned short h) {
  return __uint_as_float((unsigned)h << 16);
}

// ---------------------------------------------------------------------------
// Weight pre-transform (3x3 layers): W f32 [Co][Ci][3][3] -> bf16 hi/lo frags.
// frag(cot,ch,tap,cg,h) at shorts: (cot*nch+ch)*36864 + tap*4096 + cg*1024
//                                  + h*512 + lane*8
// ---------------------------------------------------------------------------
__global__ __launch_bounds__(256) void k_wxform(const float* __restrict__ Wsrc,
                                                unsigned short* __restrict__ wt,
                                                int Ci, int Co) {
  const int nch = Ci >> 5;
  const int total = (Co >> 6) * nch * 9 * 4 * 64;
  int idx = blockIdx.x * 256 + threadIdx.x;
  if (idx >= total) return;
  int lane = idx & 63;
  int t2 = idx >> 6;
  int cg = t2 & 3;
  int t3 = t2 >> 2;
  int tap = t3 % 9;
  int t4 = t3 / 9;
  int ch = t4 % nch;
  int cot = t4 / nch;
  int co = cot * 64 + cg * 16 + (lane & 15);
  int cib = ch * 32 + (lane >> 4) * 8;
  short8 vh, vl;
  #pragma unroll
  for (int j = 0; j < 8; ++j) {
    float wv = Wsrc[((size_t)co * Ci + cib + j) * 9 + tap];
    unsigned short h = f2bf_rne(wv);
    vh[j] = (short)h;
    vl[j] = (short)f2bf_rne(wv - bf2f(h));
  }
  size_t base = ((((size_t)cot * nch + ch) * 9 + tap) * 4 + cg) * 1024 + (size_t)lane * 8;
  *(short8*)&wt[base] = vh;
  *(short8*)&wt[base + 512] = vl;
}

// L1 weight transform: W f32 [128][3][3][3] -> K=32 frags, k = tap*3+ci.
__global__ __launch_bounds__(256) void k_wxform1(const float* __restrict__ Wsrc,
                                                 unsigned short* __restrict__ wt) {
  int idx = blockIdx.x * 256 + threadIdx.x;   // 512 total
  if (idx >= 512) return;
  int lane = idx & 63, cg = (idx >> 6) & 3, cot = idx >> 8;
  int co = cot * 64 + cg * 16 + (lane & 15);
  short8 vh, vl;
  #pragma unroll
  for (int e = 0; e < 8; ++e) {
    int k = (lane >> 4) * 8 + e;
    float wv = 0.f;
    if (k < 27) { int tap = k / 3, ci = k - 3 * tap; wv = Wsrc[(co * 3 + ci) * 9 + tap]; }
    unsigned short h = f2bf_rne(wv);
    vh[e] = (short)h;
    vl[e] = (short)f2bf_rne(wv - bf2f(h));
  }
  size_t base = (size_t)cot * 4096 + cg * 1024 + (size_t)lane * 8;
  *(short8*)&wt[base] = vh;
  *(short8*)&wt[base + 512] = vl;
}

// Transpose+pack x: [n][c][hw][t] f32 -> XT2[(n*64+t)][c][hw] u32 = hi|lo<<16
__global__ __launch_bounds__(256) void k_tpack(const float* __restrict__ x,
                                               unsigned* __restrict__ XT2) {
  int idx = blockIdx.x * 256 + threadIdx.x;   // 786432
  int b = idx / 3072;
  int rem = idx - b * 3072;
  int t = b & 63, n = b >> 6;
  float f = x[((size_t)(n * 3072 + rem)) * 64 + t];
  unsigned short h = f2bf_rne(f);
  unsigned short l = f2bf_rne(f - bf2f(h));
  XT2[idx] = (unsigned)h | ((unsigned)l << 16);
}

__global__ __launch_bounds__(256) void k_xbar_pack(const float* __restrict__ x,
                                                   unsigned* __restrict__ xb) {
  int idx = blockIdx.x * 256 + threadIdx.x;   // 12288
  if (idx >= 12288) return;
  const float* p = x + (size_t)idx * 64;
  float s = 0.f;
  #pragma unroll
  for (int t = 0; t < 64; ++t) s += p[t];
  s *= 0.015625f;
  unsigned short h = f2bf_rne(s);
  unsigned short l = f2bf_rne(s - bf2f(h));
  xb[idx] = (unsigned)h | ((unsigned)l << 16);
}

// ---------------------------------------------------------------------------
// MFMA conv, generic 3x3. PAD0=false: pad=1 square W; PAD0=true: L7 (4x4->2x2).
// Block: 256 thr / 4 waves; wave-tile 64co x (G*16)px. A from global (per-tap
// double buffer), B from LDS (stride-40-short rows, conflict-free b128).
// grid.z = K-split: chunks [z*nchPer, (z+1)*nchPer), out += z*osplit,
// bias added only by z==0.
// ---------------------------------------------------------------------------
template <typename T, bool PAD0, int G>
__global__ __launch_bounds__(256, 1) void k_cmfma(
    const T* __restrict__ in, const unsigned short* __restrict__ wt,
    const float* __restrict__ bs, float* __restrict__ out,
    int Ci, int Co, int W, int TRI, int tpi, int NIMG, int nImgValid,
    int nchPer, size_t osplit) {
  constexpr int MT = 4 * G * 16;             // block m-tile
  constexpr int PPXMAX = PAD0 ? (MT / 4) * 16 : (G >= 4 ? 400 : 208);
  __shared__ unsigned short sIn[PPXMAX * 40];
  const int tid = threadIdx.x;
  const int lane = tid & 63;
  const int wv = tid >> 6;
  const int cot = blockIdx.x;
  const int mtile = blockIdx.y;
  const int kz = blockIdx.z;
  const int nch = Ci >> 5;
  const int nchA = kz * nchPer, nchB = nchA + nchPer;
  out += (size_t)kz * osplit;
  const int addBias = (kz == 0);

  int img_first, r0 = 0, PPR, PPX;
  if constexpr (PAD0) {
    img_first = mtile * (MT / 4);
    PPR = 16; PPX = (MT / 4) * 16;
  } else {
    img_first = (mtile / tpi) * NIMG;
    r0 = (mtile % tpi) * TRI;
    PPR = (TRI + 2) * (W + 2);
    PPX = NIMG * PPR;
  }
  const int TRW = TRI * W;

  // output / B-fragment mapping
  int p0[G], mimg[G], mopx[G];
  #pragma unroll
  for (int g = 0; g < G; ++g) {
    int m = wv * (G * 16) + g * 16 + (lane & 15);
    int limg;
    if constexpr (PAD0) {
      limg = m >> 2;
      int o = m & 3;
      p0[g] = limg * 16 + (o >> 1) * 4 + (o & 1);
      mopx[g] = (o >> 1) * 2 + (o & 1);
    } else {
      limg = m / TRW;
      int rm = m - limg * TRW;
      int r = rm / W, c = rm - r * W;
      p0[g] = limg * PPR + r * (W + 2) + c;
      mopx[g] = (r0 + r) * W + c;
    }
    mimg[g] = img_first + limg;
  }
  int psh[9];
  #pragma unroll
  for (int t = 0; t < 9; ++t) {
    int dh = t / 3, dw = t - dh * 3;
    psh[t] = PAD0 ? (dh * 4 + dw) : (dh * (W + 2) + dw);
  }

  // staging precompute (<=2 px per thread), idiv only here
  const int HWin = PAD0 ? 16 : W * W;
  int sgofs[2]; bool svalid[2];
  #pragma unroll
  for (int i = 0; i < 2; ++i) {
    int p = tid + i * 256;
    svalid[i] = false; sgofs[i] = 0;
    if (p < PPX) {
      int limg, gpx;
      if constexpr (PAD0) {
        limg = p >> 4; gpx = p & 15;
      } else {
        limg = p / PPR;
        int rem = p - limg * PPR;
        int pr = rem / (W + 2), pc = rem - pr * (W + 2);
        int gr = r0 + pr - 1, gc = pc - 1;
        gpx = (gr >= 0 && gr < W && gc >= 0 && gc < W) ? gr * W + gc : -1;
      }
      int img = img_first + limg;
      if (gpx >= 0 && img < nImgValid) {
        svalid[i] = true;
        sgofs[i] = img * Ci * HWin + gpx;
      }
    }
  }
  const int kb = (lane >> 4) * 8;

  floatx4 acc[4][G];
  floatx4 zero = {0.f, 0.f, 0.f, 0.f};
  #pragma unroll
  for (int cg = 0; cg < 4; ++cg)
    #pragma unroll
    for (int g = 0; g < G; ++g) acc[cg][g] = zero;

  for (int ch = nchA; ch < nchB; ++ch) {
    const int ci0 = ch * 32;
    // ---- stage input patch [px][32 ci] as bf16, packed b128 writes ----
    #pragma unroll
    for (int i = 0; i < 2; ++i) {
      int p = tid + i * 256;
      if (p < PPX) {
        unsigned short* dst = &sIn[p * 40];
        if (svalid[i]) {
          const T* sp = in + sgofs[i] + (size_t)ci0 * HWin;
          #pragma unroll
          for (int j = 0; j < 4; ++j) {
            short8 v;
            #pragma unroll
            for (int e = 0; e < 8; ++e) {
              if constexpr (sizeof(T) == 1)
                v[e] = sp[(size_t)(j * 8 + e) * HWin] ? (short)0x3F80 : (short)0;
              else
                v[e] = (short)f2bf_rne(((const float*)sp)[(size_t)(j * 8 + e) * HWin]);
            }
            *(short8*)&dst[j * 8] = v;
          }
        } else {
          short8 z = {};
          #pragma unroll
          for (int j = 0; j < 4; ++j) *(short8*)&dst[j * 8] = z;
        }
      }
    }
    __syncthreads();
    // ---- taps: A from global (double-buffered), B from LDS ----
    const unsigned short* wb = wt + ((size_t)(cot * nch + ch)) * 36864 + (size_t)lane * 8;
    short8 A[2][8];
    #pragma unroll
    for (int f = 0; f < 8; ++f)
      A[0][f] = *(const short8*)(wb + (f >> 1) * 1024 + (f & 1) * 512);
    #pragma unroll
    for (int t = 0; t < 9; ++t) {
      const int cur = t & 1;
      if (t < 8) {
        #pragma unroll
        for (int f = 0; f < 8; ++f)
          A[cur ^ 1][f] = *(const short8*)(wb + (size_t)(t + 1) * 4096 + (f >> 1) * 1024 + (f & 1) * 512);
      }
      short8 b[G];
      #pragma unroll
      for (int g = 0; g < G; ++g)
        b[g] = *(const short8*)&sIn[(p0[g] + psh[t]) * 40 + kb];
      #pragma unroll
      for (int cg = 0; cg < 4; ++cg) {
        #pragma unroll
        for (int g = 0; g < G; ++g) {
          acc[cg][g] = __builtin_amdgcn_mfma_f32_16x16x32_bf16(A[cur][cg * 2 + 0], b[g], acc[cg][g], 0, 0, 0);
          acc[cg][g] = __builtin_amdgcn_mfma_f32_16x16x32_bf16(A[cur][cg * 2 + 1], b[g], acc[cg][g], 0, 0, 0);
        }
      }
    }
    __syncthreads();
  }
  // ---- epilogue: row=(lane>>4)*4+i -> co, col=lane&15 -> px ----
  const int HWout = PAD0 ? 4 : W * W;
  #pragma unroll
  for (int g = 0; g < G; ++g) {
    if (mimg[g] >= nImgValid) continue;
    #pragma unroll
    for (int cg = 0; cg < 4; ++cg) {
      #pragma unroll
      for (int i2 = 0; i2 < 4; ++i2) {
        int co = cot * 64 + cg * 16 + (lane >> 4) * 4 + i2;
        float bv = addBias ? bs[co] : 0.f;
        out[((size_t)mimg[g] * Co + co) * HWout + mopx[g]] = acc[cg][g][i2] + bv;
      }
    }
  }
}

// ---------------------------------------------------------------------------
// L1 MFMA conv: K=32 im2col (k=tap*3+ci), input packed hi/lo u32.
// ---------------------------------------------------------------------------
__global__ __launch_bounds__(256, 1) void k_l1(const unsigned* __restrict__ xin,
                                               const unsigned short* __restrict__ wt,
                                               const float* __restrict__ bs,
                                               float* __restrict__ out,
                                               int nImgValid) {
  __shared__ unsigned short sIn[256 * 72];   // [m][hi(32) | lo(32)], stride 72
  const int tid = threadIdx.x, lane = tid & 63, wv = tid >> 6;
  const int cot = blockIdx.x, mtile = blockIdx.y;
  const int img = mtile >> 2;
  const int r0 = (mtile & 3) * 8;
  {
    int m = tid;
    int r = r0 + (m >> 5), c = m & 31;
    const unsigned* ip = xin + (size_t)img * 3072;
    unsigned v[9][3];
    bool iv = (img < nImgValid);
    #pragma unroll
    for (int dh = 0; dh < 3; ++dh) {
      #pragma unroll
      for (int dw = 0; dw < 3; ++dw) {
        int rr = r + dh - 1, cc = c + dw - 1;
        bool ok = iv && rr >= 0 && rr < 32 && cc >= 0 && cc < 32;
        #pragma unroll
        for (int ci = 0; ci < 3; ++ci)
          v[dh * 3 + dw][ci] = ok ? ip[ci * 1024 + rr * 32 + cc] : 0u;
      }
    }
    #pragma unroll
    for (int j = 0; j < 4; ++j) {
      short8 vh, vl;
      #pragma unroll
      for (int e = 0; e < 8; ++e) {
        int k = j * 8 + e;
        unsigned u = (k < 27) ? v[k / 3][k - 3 * (k / 3)] : 0u;
        vh[e] = (short)(u & 0xFFFFu);
        vl[e] = (short)(u >> 16);
      }
      *(short8*)&sIn[m * 72 + j * 8] = vh;
      *(short8*)&sIn[m * 72 + 32 + j * 8] = vl;
    }
  }
  __syncthreads();
  const int kb = (lane >> 4) * 8;
  const unsigned short* wb = wt + (size_t)cot * 4096 + (size_t)lane * 8;
  short8 Af[8];
  #pragma unroll
  for (int f = 0; f < 8; ++f)
    Af[f] = *(const short8*)(wb + (f >> 1) * 1024 + (f & 1) * 512);
  floatx4 acc[4][4];
  floatx4 zero = {0.f, 0.f, 0.f, 0.f};
  #pragma unroll
  for (int cg = 0; cg < 4; ++cg)
    #pragma unroll
    for (int g = 0; g < 4; ++g) acc[cg][g] = zero;
  short8 bh[4], bl[4];
  #pragma unroll
  for (int g = 0; g < 4; ++g) {
    int m = wv * 64 + g * 16 + (lane & 15);
    bh[g] = *(const short8*)&sIn[m * 72 + kb];
    bl[g] = *(const short8*)&sIn[m * 72 + 32 + kb];
  }
  #pragma unroll
  for (int cg = 0; cg < 4; ++cg) {
    #pragma unroll
    for (int g = 0; g < 4; ++g) {
      acc[cg][g] = __builtin_amdgcn_mfma_f32_16x16x32_bf16(Af[cg * 2 + 0], bh[g], acc[cg][g], 0, 0, 0);
      acc[cg][g] = __builtin_amdgcn_mfma_f32_16x16x32_bf16(Af[cg * 2 + 0], bl[g], acc[cg][g], 0, 0, 0);
      acc[cg][g] = __builtin_amdgcn_mfma_f32_16x16x32_bf16(Af[cg * 2 + 1], bh[g], acc[cg][g], 0, 0, 0);
    }
  }
  if (img >= nImgValid) return;
  #pragma unroll
  for (int g = 0; g < 4; ++g) {
    int mbase = wv * 64 + g * 16 + (lane & 15);
    int px = (r0 + (mbase >> 5)) * 32 + (mbase & 31);
    #pragma unroll
    for (int cg = 0; cg < 4; ++cg) {
      #pragma unroll
      for (int i2 = 0; i2 < 4; ++i2) {
        int co = cot * 64 + cg * 16 + (lane >> 4) * 4 + i2;
        out[((size_t)img * 128 + co) * 1024 + px] = acc[cg][g][i2] + bs[co];
      }
    }
  }
}

// ---------------------------------------------------------------------------
__global__ __launch_bounds__(256) void k_pool_u8(const uint8_t* __restrict__ in,
                                                 float* __restrict__ out,
                                                 int H, int total) {
  int idx = blockIdx.x * 256 + threadIdx.x;
  if (idx >= total) return;
  int Wo = H >> 1;
  int wo = idx % Wo;
  int t1 = idx / Wo;
  int ho = t1 % Wo;
  int bc = t1 / Wo;
  size_t base = ((size_t)bc * H + 2 * ho) * H + 2 * wo;
  out[idx] = 0.25f * ((float)in[base] + (float)in[base + 1] +
                      (float)in[base + H] + (float)in[base + H + 1]);
}

__global__ __launch_bounds__(256) void k_pool_f32(const float* __restrict__ in,
                                                  float* __restrict__ out,
                                                  int H, int total) {
  int idx = blockIdx.x * 256 + threadIdx.x;
  if (idx >= total) return;
  int Wo = H >> 1;
  int wo = idx % Wo;
  int t1 = idx / Wo;
  int ho = t1 % Wo;
  int bc = t1 / Wo;
  size_t base = ((size_t)bc * H + 2 * ho) * H + 2 * wo;
  out[idx] = 0.25f * (in[base] + in[base + 1] + in[base + H] + in[base + H + 1]);
}

// Integrate-and-fire; blockIdx.y = 64-t group. Sums nparts partials (stride
// pstride elements) before integrating.
__global__ __launch_bounds__(256) void k_if(const float* __restrict__ X,
                                            uint8_t* __restrict__ Sp,
                                            const float* __restrict__ th,
                                            float* __restrict__ ssum,
                                            int C, int HW,
                                            int nparts, size_t pstride) {
  const int CHW = C * HW;
  int idx = blockIdx.x * 256 + threadIdx.x;
  if (idx >= CHW) return;
  int c = idx / HW;
  const float thv = th[c];
  size_t base = (size_t)blockIdx.y * 64 * CHW + idx;
  const float* p = X + base;
  uint8_t* q = Sp + base;
  float v = 0.f, ss = 0.f;
  #pragma unroll
  for (int t = 0; t < 64; ++t) {
    const float* pt = p + (size_t)t * CHW;
    float xv = pt[0];
    for (int u = 1; u < nparts; ++u) xv += pt[(size_t)u * pstride];
    v += xv;
    float s = (v >= thv) ? 1.f : 0.f;
    v -= s * thv;
    q[(size_t)t * CHW] = (uint8_t)s;
    ss += s;
  }
  if ((HW & 63) == 0) {
    for (int off = 32; off >= 1; off >>= 1) ss += __shfl_down(ss, off);
    if ((threadIdx.x & 63) == 0) atomicAdd(&ssum[c], ss);
  } else {
    atomicAdd(&ssum[c], ss);
  }
}

// Analog quantize; sums nparts partial conv outputs (K-split) first.
__global__ __launch_bounds__(256) void k_tty(const float* __restrict__ y4,
                                             float* __restrict__ yout,
                                             float* __restrict__ ysum,
                                             int C, int HW,
                                             int nparts, int pstride) {
  int idx = blockIdx.x * 256 + threadIdx.x;
  if (idx >= 4 * C * HW) return;
  int rem = idx % (C * HW);
  int c = rem / HW;
  float xv = 0.f;
  for (int p = 0; p < nparts; ++p) xv += y4[idx + (size_t)p * pstride];
  float v = floorf(xv * 64.f) * 0.015625f;
  v = fminf(fmaxf(v, 0.f), 1.f);
  yout[idx] = v;
  if ((HW & 63) == 0) {
    for (int off = 32; off >= 1; off >>= 1) v += __shfl_down(v, off);
    if ((threadIdx.x & 63) == 0) atomicAdd(&ysum[c], v);
  } else {
    atomicAdd(&ysum[c], v);
  }
}

__global__ void k_thr(const float* __restrict__ thin,
                      const float* __restrict__ ssum,
                      const float* __restrict__ ysum,
                      float* __restrict__ dst, int C, float invmul) {
  int c = blockIdx.x * 256 + threadIdx.x;
  if (c >= C) return;
  float diff = (ysum[c] * 64.f - ssum[c]) * invmul;
  dst[c] = thin[c] - 0.1f * diff;
}

__global__ void k_sumspk(const uint8_t* __restrict__ A, float* __restrict__ S) {
  int idx = blockIdx.x * 256 + threadIdx.x;
  if (idx >= 4096) return;
  int n = idx >> 10, c = idx & 1023;
  const uint8_t* p = A + (size_t)n * 64 * 1024 + c;
  float s = 0.f;
  #pragma unroll
  for (int t = 0; t < 64; ++t) s += (float)p[t * 1024];
  S[idx] = s;
}

__global__ void k_cls(const float* __restrict__ S, const float* __restrict__ wc,
                      const float* __restrict__ bcp, float* __restrict__ out) {
  int idx = blockIdx.x * 256 + threadIdx.x;
  if (idx >= 400) return;
  int n = idx / 100, o = idx - (idx / 100) * 100;
  const float* sp = S + n * 1024;
  const float* wp = wc + o * 1024;
  float acc = 0.f;
  for (int c = 0; c < 1024; ++c) acc += wp[c] * sp[c];
  out[idx] = acc * 0.015625f + bcp[o];
}

extern "C" void kernel_launch(void* const* d_in, const int* in_sizes, int n_in,
                              void* d_out_v, int out_size, void* d_ws, size_t ws_size,
                              hipStream_t stream) {
  const float *Ws[7], *Bs[7], *Wa[7], *Ba[7];
  for (int i = 0; i < 7; ++i) {
    Ws[i] = (const float*)d_in[i * 4 + 0];
    Bs[i] = (const float*)d_in[i * 4 + 1];
    Wa[i] = (const float*)d_in[i * 4 + 2];
    Ba[i] = (const float*)d_in[i * 4 + 3];
  }
  const float* wc = (const float*)d_in[28];
  const float* bc = (const float*)d_in[29];
  const float* x  = (const float*)d_in[30];
  const float* TH[7];
  for (int i = 0; i < 7; ++i) TH[i] = (const float*)d_in[31 + i];
  const float* P[4];
  for (int i = 0; i < 4; ++i) P[i] = (const float*)d_in[38 + i];
  float* out = (float*)d_out_v;

  // ---- workspace (107.7 MB) ----
  float* w = (float*)d_ws;
  const size_t RF = 8536064;      // [WT | CF0] region, per-layer split
  float* Rb = w;
  size_t off = RF;
  float* xbar = w + off; off += 12288;    // packed u32 hi/lo
  float* yA   = w + off; off += 524288;
  float* yB   = w + off; off += 524288;
  float* y4   = w + off; off += 524288;
  float* S    = w + off; off += 4096;
  float* sums = w + off; off += 11 * 2048;
  uint8_t* SA = (uint8_t*)(w + off);
  uint8_t* SB = SA + 33554432;
  size_t total_bytes = off * sizeof(float) + (size_t)2 * 33554432;
  if (ws_size < total_bytes) return;
  unsigned short* WT = (unsigned short*)Rb;
  unsigned* XT2 = (unsigned*)SB;          // aliases SB (dead until L2 output)
  unsigned* xbar2 = (unsigned*)xbar;

  hipMemsetAsync(sums, 0, 11 * 2048 * sizeof(float), stream);
  k_tpack<<<3072, 256, 0, stream>>>(x, XT2);
  k_xbar_pack<<<48, 256, 0, stream>>>(x, xbar2);

  int stage = 0;

  // ---- L1 (MFMA im2col) ----
  {
    float* CF = Rb + 4096;                 // WT1 = 16 KB
    float* ss = sums; float* ys = ss + 1024;
    k_wxform1<<<2, 256, 0, stream>>>(Ws[0], WT);
    for (int c = 0; c < 4; ++c) {
      k_l1<<<dim3(2, 256), 256, 0, stream>>>(XT2 + (size_t)c * 64 * 3072, WT, Bs[0], CF, 64);
      k_if<<<dim3(512, 1), 256, 0, stream>>>(CF, SA + (size_t)c * 64 * 131072,
                                             TH[0], ss, 128, 1024, 1, 0);
    }
    k_wxform1<<<2, 256, 0, stream>>>(Wa[0], WT);
    k_l1<<<dim3(2, 16), 256, 0, stream>>>(xbar2, WT, Ba[0], y4, 4);
    k_tty<<<2048, 256, 0, stream>>>(y4, yA, ys, 128, 1024, 1, 0);
    k_thr<<<1, 256, 0, stream>>>(TH[0], ss, ys, out + 400, 128, 1.0f / (4.f * 1024.f * 64.f));
    ++stage;
  }

  // ---- generic pad=1 MFMA layer ----
  // Spike conv: G=2 tile (grid >=1024), optional kz (partials at CF1).
  // Analog conv (batch 4): G=1 tile, aTRI/atpi geometry, akz K-split in y4.
  auto mfma_layer = [&](const uint8_t* inS, uint8_t* outS, const float* inY, float* outY,
                        int li, int Ci, int Co, int W, int TRI, int tpi, int NIMG,
                        int chunkImgs, int kzn, float* CF1,
                        int aTRI, int atpi, int akz,
                        const float* thin, int outoff) {
    const int HW = W * W;
    const int CHWo = Co * HW;
    const int nch = Ci >> 5;
    float* ss = sums + stage * 2048; float* ys = ss + 1024;
    float* CF = Rb + (size_t)Co * Ci * 9;
    size_t osplit = (kzn == 2) ? (size_t)(CF1 - CF) : 0;
    int xgrid = ((Co / 64) * nch * 9 * 4 * 64 + 255) / 256;
    k_wxform<<<xgrid, 256, 0, stream>>>(Ws[li], WT, Ci, Co);
    int nchk = 256 / chunkImgs;
    int mt = (chunkImgs / NIMG) * tpi;
    for (int c = 0; c < nchk; ++c) {
      k_cmfma<uint8_t, false, 2><<<dim3(Co / 64, mt, kzn), 256, 0, stream>>>(
          inS + (size_t)c * chunkImgs * Ci * HW, WT, Bs[li], CF,
          Ci, Co, W, TRI, tpi, NIMG, chunkImgs, nch / kzn, osplit);
      k_if<<<dim3((CHWo + 255) / 256, chunkImgs / 64), 256, 0, stream>>>(
          CF, outS + (size_t)c * chunkImgs * CHWo, thin, ss, Co, HW, kzn, osplit);
    }
    k_wxform<<<xgrid, 256, 0, stream>>>(Wa[li], WT, Ci, Co);
    int aosplit = 4 * CHWo;
    k_cmfma<float, false, 1><<<dim3(Co / 64, 4 * atpi, akz), 256, 0, stream>>>(
        inY, WT, Ba[li], y4, Ci, Co, W, aTRI, atpi, 1, 4, nch / akz, (size_t)aosplit);
    k_tty<<<(4 * CHWo + 255) / 256, 256, 0, stream>>>(y4, outY, ys, Co, HW, akz, aosplit);
    k_thr<<<(Co + 255) / 256, 256, 0, stream>>>(thin, ss, ys, out + outoff, Co,
                                                1.0f / (4.f * HW * 64.f));
    ++stage;
  };

  auto pool_stage = [&](const uint8_t* inS, uint8_t* outS, const float* inY, float* outY,
                        int C, int H, const float* pthr, int outoff) {
    const int Ho = H / 2, HWo = Ho * Ho;
    const int CHWo = C * HWo;
    float* CF = Rb;
    float* ss = sums + stage * 2048; float* ys = ss + 1024;
    int tot5 = 256 * CHWo;
    k_pool_u8<<<(tot5 + 255) / 256, 256, 0, stream>>>(inS, CF, H, tot5);
    k_if<<<dim3((CHWo + 255) / 256, 4), 256, 0, stream>>>(CF, outS, pthr, ss, C, HWo, 1, 0);
    int tot4 = 4 * CHWo;
    k_pool_f32<<<(tot4 + 255) / 256, 256, 0, stream>>>(inY, y4, H, tot4);
    k_tty<<<(tot4 + 255) / 256, 256, 0, stream>>>(y4, outY, ys, C, HWo, 1, 0);
    k_thr<<<(C + 255) / 256, 256, 0, stream>>>(pthr, ss, ys, out + outoff, C,
                                               1.0f / (4.f * HWo * 64.f));
    ++stage;
  };

  // L2: spike G=2 TRI=4,tpi=8 -> grid(2,512,1)=1024; analog aTRI=2,atpi=16
  mfma_layer(SA, SB, yA, yB, 1, 128, 128, 32, 4, 8, 1, 64, 1, nullptr,
             2, 16, 1, TH[1], 528);
  // P1
  pool_stage(SB, SA, yB, yA, 128, 32, P[0], 3216);
  // L3: spike TRI=8,tpi=2, kz=2 (partial SB tail) -> grid(4,128,2)=1024
  mfma_layer(SA, SB, yA, yB, 2, 128, 256, 16, 8, 2, 1, 64, 2,
             (float*)(SB + 16777216), 4, 4, 2, TH[2], 656);
  // L4
  mfma_layer(SB, SA, yB, yA, 3, 256, 256, 16, 8, 2, 1, 64, 2,
             (float*)(SA + 16777216), 4, 4, 2, TH[3], 912);
  // P2
  pool_stage(SA, SB, yA, yB, 256, 16, P[1], 3344);
  // L5: spike NIMG=2,TRI=8,tpi=1, kz=2 -> grid(8,64,2)=1024
  mfma_layer(SB, SA, yB, yA, 4, 256, 512, 8, 8, 1, 2, 128, 2,
             (float*)(SA + 8388608), 8, 1, 4, TH[4], 1168);
  // L6
  mfma_layer(SA, SB, yA, yB, 5, 512, 512, 8, 8, 1, 2, 128, 2,
             (float*)(SB + 8388608), 8, 1, 4, TH[5], 1680);
  // P3
  pool_stage(SB, SA, yB, yA, 512, 8, P[2], 3600);
  // L7 (pad=0): spike kz=4, partials in SA tail; analog G=1 akz=8 in y4
  {
    float* ss = sums + stage * 2048; float* ys = ss + 1024;
    float* CF = (float*)(SA + 4194304);         // 4 partials x 4.2 MB
    const size_t osplit = 1048576;              // 256*1024*4 elems
    int xgrid = (16 * 16 * 9 * 4 * 64 + 255) / 256;
    k_wxform<<<xgrid, 256, 0, stream>>>(Ws[6], WT, 512, 1024);
    k_cmfma<uint8_t, true, 2><<<dim3(16, 8, 4), 256, 0, stream>>>(
        SA, WT, Bs[6], CF, 512, 1024, 4, 0, 1, 0, 256, 4, osplit);
    k_if<<<dim3(16, 4), 256, 0, stream>>>(CF, SB, TH[6], ss, 1024, 4, 4, osplit);
    k_wxform<<<xgrid, 256, 0, stream>>>(Wa[6], WT, 512, 1024);
    k_cmfma<float, true, 1><<<dim3(16, 1, 8), 256, 0, stream>>>(
        yA, WT, Ba[6], y4, 512, 1024, 4, 0, 1, 0, 4, 2, 16384);
    k_tty<<<64, 256, 0, stream>>>(y4, yB, ys, 1024, 4, 8, 16384);
    k_thr<<<4, 256, 0, stream>>>(TH[6], ss, ys, out + 2192, 1024, 1.0f / 1024.f);
    ++stage;
  }
  // P4
  pool_stage(SB, SA, yB, yA, 1024, 2, P[3], 4112);
  // classifier
  k_sumspk<<<16, 256, 0, stream>>>(SA, S);
  k_cls<<<2, 256, 0, stream>>>(S, wc, bc, out);
}